// Round 1
// baseline (2627.743 us; speedup 1.0000x reference)
//
#include <hip/hip_runtime.h>
#include <math.h>

typedef unsigned int u32;
typedef unsigned long long u64;

#define B 8
#define H 1024
#define W 1536
#define NPIX (H * W)
#define NK 2048
#define BORDER 16
#define CAND_CAP_MAX 262144

// workspace layout (bytes)
#define OFF_COUNTS 0       // u32[8]
#define OFF_KREM 64        // u32[8]
#define OFF_TCOUNT 128     // u32[8]
#define OFF_PREFIX 256     // u64[8]
#define OFF_HIST 512       // u32[8*256]
#define OFF_TOPK 16384     // u64[8*2048]
#define OFF_CAND 147456    // u64[8*cap]

__global__ void init_k(u32* counts, u32* krem, u32* tcount, u64* prefix, u32* hist) {
    int t = threadIdx.x;
    if (t < B) { counts[t] = 0; krem[t] = NK; tcount[t] = 0; prefix[t] = 0ull; }
    for (int i = t; i < B * 256; i += blockDim.x) hist[i] = 0;
}

__global__ void cand_k(const float* __restrict__ neur, const float* __restrict__ score,
                       u64* __restrict__ cand, u32* counts, int cap) {
    int x = blockIdx.x * blockDim.x + threadIdx.x;
    int y = blockIdx.y;
    int b = blockIdx.z;
    const float* s = score + (size_t)b * NPIX;
    bool is_cand = false;
    u64 key = 0;
    if (y >= BORDER && y < H - BORDER && x >= BORDER && x < W - BORDER) {
        int idx = y * W + x;
        float c = s[idx];
        bool mx = c >= s[idx - W - 1] && c >= s[idx - W] && c >= s[idx - W + 1]
               && c >= s[idx - 1] && c >= s[idx + 1]
               && c >= s[idx + W - 1] && c >= s[idx + W] && c >= s[idx + W + 1];
        if (mx) {
            float nv = fmaxf(neur[(size_t)b * NPIX + idx], 0.0f);
            float ness = (float)exp(-(double)nv);  // correctly-rounded f32 exp
            key = ((u64)__float_as_uint(ness) << 32) | (u32)(~(u32)idx);
            is_cand = true;
        }
    }
    u64 m = __ballot((int)is_cand);
    if (m) {
        int lane = threadIdx.x & 63;
        int leader = __ffsll(m) - 1;
        u32 base = 0;
        if (lane == leader) base = atomicAdd(&counts[b], (u32)__popcll(m));
        base = (u32)__shfl((int)base, leader, 64);
        if (is_cand) {
            u32 pos = base + (u32)__popcll(m & ((1ull << (u32)lane) - 1ull));
            if ((int)pos < cap) cand[(size_t)b * cap + pos] = key;
        }
    }
}

__global__ void hist_k(const u64* __restrict__ cand, const u32* __restrict__ counts,
                       const u64* __restrict__ prefix, u32* hist, int shift, int cap) {
    __shared__ u32 lh[256];
    int b = blockIdx.y;
    for (int i = threadIdx.x; i < 256; i += blockDim.x) lh[i] = 0;
    __syncthreads();
    u32 n = counts[b]; if ((int)n > cap) n = (u32)cap;
    u64 pfx = prefix[b];
    u32 stride = gridDim.x * blockDim.x;
    for (u32 i = blockIdx.x * blockDim.x + threadIdx.x; i < n; i += stride) {
        u64 key = cand[(size_t)b * cap + i];
        bool match = (shift == 56) || ((key >> (shift + 8)) == (pfx >> (shift + 8)));
        if (match) atomicAdd(&lh[(u32)(key >> shift) & 255u], 1u);
    }
    __syncthreads();
    for (int i = threadIdx.x; i < 256; i += blockDim.x)
        if (lh[i]) atomicAdd(&hist[b * 256 + i], lh[i]);
}

__global__ void scan_k(u32* hist, u64* prefix, u32* krem, int shift) {
    int t = threadIdx.x;
    if (t < B) {
        u32 k = krem[t];
        u32 c = 0;
        int dsel = 0;
        u32 below = 0;
        for (int d = 255; d >= 0; --d) {
            u32 hc = hist[t * 256 + d];
            c += hc;
            if (c >= k) { dsel = d; below = c - hc; break; }
        }
        prefix[t] |= ((u64)(u32)dsel << shift);
        krem[t] = k - below;
    }
    __syncthreads();
    for (int i = threadIdx.x; i < B * 256; i += blockDim.x) hist[i] = 0;
}

__global__ void compact_k(const u64* __restrict__ cand, const u32* __restrict__ counts,
                          const u64* __restrict__ prefix, u64* __restrict__ topk,
                          u32* tcount, int cap) {
    int b = blockIdx.y;
    u32 n = counts[b]; if ((int)n > cap) n = (u32)cap;
    u64 K = prefix[b];
    u32 stride = gridDim.x * blockDim.x;
    u32 iters = (n + stride - 1) / stride;
    for (u32 it = 0; it < iters; ++it) {
        u32 i = it * stride + blockIdx.x * blockDim.x + threadIdx.x;
        u64 key = 0;
        bool f = false;
        if (i < n) {
            key = cand[(size_t)b * cap + i];
            f = (key >= K);
        }
        u64 m = __ballot((int)f);
        if (m) {
            int lane = threadIdx.x & 63;
            int leader = __ffsll(m) - 1;
            u32 base = 0;
            if (lane == leader) base = atomicAdd(&tcount[b], (u32)__popcll(m));
            base = (u32)__shfl((int)base, leader, 64);
            if (f) {
                u32 pos = base + (u32)__popcll(m & ((1ull << (u32)lane) - 1ull));
                if (pos < NK) topk[(size_t)b * NK + pos] = key;
            }
        }
    }
}

__global__ __launch_bounds__(1024) void final_k(const float* __restrict__ neur,
                                                const float* __restrict__ score,
                                                const u64* __restrict__ topk,
                                                float* __restrict__ out) {
    __shared__ u64 keys[NK];
    int b = blockIdx.x;
    int t = threadIdx.x;
    for (int i = t; i < NK; i += blockDim.x) keys[i] = topk[(size_t)b * NK + i];
    __syncthreads();
    // bitonic sort, descending
    for (u32 k = 2; k <= NK; k <<= 1) {
        for (u32 j = k >> 1; j > 0; j >>= 1) {
            for (u32 i = (u32)t; i < NK; i += blockDim.x) {
                u32 ixj = i ^ j;
                if (ixj > i) {
                    u64 a = keys[i], c = keys[ixj];
                    bool desc = ((i & k) == 0);
                    bool sw = desc ? (a < c) : (a > c);
                    if (sw) { keys[i] = c; keys[ixj] = a; }
                }
            }
            __syncthreads();
        }
    }
    const float* s = score + (size_t)b * NPIX;
    const float* nb = neur + (size_t)b * NPIX;
    for (int i = t; i < NK; i += blockDim.x) {
        u64 key = keys[i];
        u32 idx = ~(u32)key;
        int y = (int)(idx / W), x = (int)(idx % W);
        int yc = min(max(y, 1), H - 2), xc = min(max(x, 1), W - 2);
        int p = yc * W + xc;
        float s00 = s[p], sp0 = s[p + W], sm0 = s[p - W], s0p = s[p + 1], s0m = s[p - 1];
        float spp = s[p + W + 1], spm = s[p + W - 1], smp = s[p - W + 1], smm = s[p - W - 1];
        float gy = 0.5f * (sp0 - sm0);
        float gx = 0.5f * (s0p - s0m);
        float hyy = sp0 - 2.0f * s00 + sm0;
        float hxx = s0p - 2.0f * s00 + s0m;
        float hxy = 0.25f * (spp - spm - smp + smm);
        float det = hyy * hxx - hxy * hxy;
        bool sing = fabsf(det) > 1e-12f;
        float sd = sing ? det : 1.0f;
        float iy = -(hxx * gy - hxy * gx) / sd;
        float ix = -(hyy * gx - hxy * gy) / sd;
        if (!sing) { iy = 0.0f; ix = 0.0f; }
        iy = fminf(fmaxf(iy, -0.5f), 0.5f);
        ix = fminf(fmaxf(ix, -0.5f), 0.5f);
        size_t o = ((size_t)b * NK + (size_t)i) * 3;
        out[o] = (float)y + 0.5f + iy;
        out[o + 1] = (float)x + 0.5f + ix;
        out[o + 2] = fmaxf(nb[idx], 0.0f);
    }
}

extern "C" void kernel_launch(void* const* d_in, const int* in_sizes, int n_in,
                              void* d_out, int out_size, void* d_ws, size_t ws_size,
                              hipStream_t stream) {
    const float* neur = (const float*)d_in[0];
    const float* score = (const float*)d_in[1];
    float* out = (float*)d_out;
    char* ws = (char*)d_ws;
    u32* counts = (u32*)(ws + OFF_COUNTS);
    u32* krem = (u32*)(ws + OFF_KREM);
    u32* tcount = (u32*)(ws + OFF_TCOUNT);
    u64* prefix = (u64*)(ws + OFF_PREFIX);
    u32* hist = (u32*)(ws + OFF_HIST);
    u64* topk = (u64*)(ws + OFF_TOPK);
    u64* cand = (u64*)(ws + OFF_CAND);

    size_t avail = ws_size > OFF_CAND ? ws_size - OFF_CAND : 0;
    long long cap_ll = (long long)(avail / (8ull * (u64)B));
    int cap = cap_ll > CAND_CAP_MAX ? CAND_CAP_MAX : (int)cap_ll;

    init_k<<<1, 256, 0, stream>>>(counts, krem, tcount, prefix, hist);
    cand_k<<<dim3(W / 256, H, B), 256, 0, stream>>>(neur, score, cand, counts, cap);
    for (int p = 7; p >= 0; --p) {
        int shift = 8 * p;
        hist_k<<<dim3(32, B), 256, 0, stream>>>(cand, counts, prefix, hist, shift, cap);
        scan_k<<<1, 256, 0, stream>>>(hist, prefix, krem, shift);
    }
    compact_k<<<dim3(32, B), 256, 0, stream>>>(cand, counts, prefix, topk, tcount, cap);
    final_k<<<B, 1024, 0, stream>>>(neur, score, topk, out);
}

// Round 2
// 476.627 us; speedup vs baseline: 5.5132x; 5.5132x over previous
//
#include <hip/hip_runtime.h>
#include <math.h>

typedef unsigned int u32;
typedef unsigned long long u64;

#define B 8
#define H 1024
#define W 1536
#define NPIX (H * W)
#define NK 2048
#define BORDER 16
#define NSEG 64
#define SEG_CAP_MAX 4096
#define TOPK_CAP 4096
#define CTR_PAD 32  // u32s per counter slot (128 B line each)

// workspace layout (bytes)
#define OFF_KREM 0          // u32[8]
#define OFF_PREFIX 64       // u32[8]
#define OFF_TCOUNT 128      // u32[8*CTR_PAD]
#define OFF_HIST 4096       // u32[8*256]
#define OFF_SEGCNT 16384    // u32[8*64*CTR_PAD] = 64 KB
#define OFF_TOPK 81920      // u32[8*TOPK_CAP] = 128 KB
#define OFF_CANDF 212992    // u32[8*64*seg_cap]
// candi follows candf

__global__ void init_k(u32* krem, u32* prefix, u32* tcount, u32* hist, u32* segcnt) {
    u32 t = blockIdx.x * blockDim.x + threadIdx.x;
    u32 stride = gridDim.x * blockDim.x;
    for (u32 i = t; i < B; i += stride) { krem[i] = NK; prefix[i] = 0; }
    for (u32 i = t; i < B * CTR_PAD; i += stride) tcount[i] = 0;
    for (u32 i = t; i < B * 256; i += stride) hist[i] = 0;
    for (u32 i = t; i < B * NSEG * CTR_PAD; i += stride) segcnt[i] = 0;
}

__global__ void cand_k(const float* __restrict__ neur, const float* __restrict__ score,
                       u32* __restrict__ candf, u32* __restrict__ candi,
                       u32* __restrict__ segcnt, int seg_cap) {
    int x = blockIdx.x * blockDim.x + threadIdx.x;
    int y = BORDER + blockIdx.y;
    int b = blockIdx.z;
    const float* s = score + (size_t)b * NPIX;
    bool is_cand = false;
    u32 fbits = 0;
    u32 idx = 0;
    if (x >= BORDER && x < W - BORDER) {
        idx = (u32)(y * W + x);
        float c = s[idx];
        bool mx = c >= s[idx - W - 1] && c >= s[idx - W] && c >= s[idx - W + 1]
               && c >= s[idx - 1] && c >= s[idx + 1]
               && c >= s[idx + W - 1] && c >= s[idx + W] && c >= s[idx + W + 1];
        if (mx) {
            float nv = fmaxf(neur[(size_t)b * NPIX + idx], 0.0f);
            fbits = __float_as_uint(nv);  // nv >= 0: bits are order-monotone
            is_cand = true;
        }
    }
    u64 m = __ballot((int)is_cand);
    if (m) {
        int lane = threadIdx.x & 63;
        int leader = __ffsll(m) - 1;
        int seg = y & (NSEG - 1);
        u32* ctr = &segcnt[(u32)(b * NSEG + seg) * CTR_PAD];
        u32 base = 0;
        if (lane == leader) base = atomicAdd(ctr, (u32)__popcll(m));
        base = (u32)__shfl((int)base, leader, 64);
        if (is_cand) {
            u32 pos = base + (u32)__popcll(m & ((1ull << (u32)lane) - 1ull));
            if ((int)pos < seg_cap) {
                u32 slot = (u32)(b * NSEG + seg) * (u32)seg_cap + pos;
                candf[slot] = fbits;
                candi[slot] = idx;
            }
        }
    }
}

__global__ void hist_k(const u32* __restrict__ candf, const u32* __restrict__ segcnt,
                       const u32* __restrict__ prefix, u32* hist, int shift, int seg_cap) {
    __shared__ u32 lh[256];
    int b = blockIdx.y;
    lh[threadIdx.x] = 0;
    __syncthreads();
    u32 pfx = prefix[b];
    u32 t0 = blockIdx.x * blockDim.x + threadIdx.x;
    u32 stride = gridDim.x * blockDim.x;
    for (int seg = 0; seg < NSEG; ++seg) {
        u32 cnt = segcnt[(u32)(b * NSEG + seg) * CTR_PAD];
        if ((int)cnt > seg_cap) cnt = (u32)seg_cap;
        u32 base = (u32)(b * NSEG + seg) * (u32)seg_cap;
        for (u32 i = t0; i < cnt; i += stride) {
            u32 f = candf[base + i];
            bool match = (shift == 24) || ((f >> (shift + 8)) == (pfx >> (shift + 8)));
            if (match) atomicAdd(&lh[(f >> shift) & 255u], 1u);
        }
    }
    __syncthreads();
    if (lh[threadIdx.x]) atomicAdd(&hist[b * 256 + threadIdx.x], lh[threadIdx.x]);
}

__global__ void scan_k(u32* hist, u32* prefix, u32* krem, int shift) {
    int t = threadIdx.x;
    if (t < B) {
        u32 k = krem[t];
        u32 cum = 0;
        u32 sel = 255, below = 0;
        for (int d = 0; d < 256; ++d) {  // ascending: k-th SMALLEST nv
            u32 h = hist[t * 256 + d];
            cum += h;
            if (cum >= k) { sel = (u32)d; below = cum - h; break; }
        }
        prefix[t] |= (sel << shift);
        krem[t] = k - below;
    }
    __syncthreads();
    for (int i = threadIdx.x; i < B * 256; i += blockDim.x) hist[i] = 0;
}

__global__ void compact_k(const u32* __restrict__ candf, const u32* __restrict__ candi,
                          const u32* __restrict__ segcnt, const u32* __restrict__ prefix,
                          u32* __restrict__ topkidx, u32* tcount, int seg_cap) {
    int b = blockIdx.y;
    u32 piv = prefix[b] + 512u;  // +512 ulp slack: captures all exp-rounding ties
    u32 t0 = blockIdx.x * blockDim.x + threadIdx.x;
    u32 stride = gridDim.x * blockDim.x;
    int lane = threadIdx.x & 63;
    for (int seg = 0; seg < NSEG; ++seg) {
        u32 cnt = segcnt[(u32)(b * NSEG + seg) * CTR_PAD];
        if ((int)cnt > seg_cap) cnt = (u32)seg_cap;
        u32 base = (u32)(b * NSEG + seg) * (u32)seg_cap;
        u32 iters = (cnt + stride - 1) / stride;
        for (u32 it = 0; it < iters; ++it) {
            u32 i = it * stride + t0;
            bool f = false;
            u32 idx = 0;
            if (i < cnt) {
                f = (candf[base + i] <= piv);
                if (f) idx = candi[base + i];
            }
            u64 m = __ballot((int)f);
            if (m) {
                int leader = __ffsll(m) - 1;
                u32 wbase = 0;
                if (lane == leader) wbase = atomicAdd(&tcount[b * CTR_PAD], (u32)__popcll(m));
                wbase = (u32)__shfl((int)wbase, leader, 64);
                if (f) {
                    u32 pos = wbase + (u32)__popcll(m & ((1ull << (u32)lane) - 1ull));
                    if (pos < TOPK_CAP) topkidx[(u32)b * TOPK_CAP + pos] = idx;
                }
            }
        }
    }
}

__global__ __launch_bounds__(1024) void final_k(const float* __restrict__ neur,
                                                const float* __restrict__ score,
                                                const u32* __restrict__ topkidx,
                                                const u32* __restrict__ tcount,
                                                float* __restrict__ out) {
    __shared__ u64 keys[TOPK_CAP];
    int b = blockIdx.x;
    int t = threadIdx.x;
    u32 cnt = tcount[b * CTR_PAD];
    if (cnt > TOPK_CAP) cnt = TOPK_CAP;
    const float* nb = neur + (size_t)b * NPIX;
    for (u32 i = (u32)t; i < TOPK_CAP; i += blockDim.x) {
        u64 key = 0;
        if (i < cnt) {
            u32 idx = topkidx[(u32)b * TOPK_CAP + i];
            float nv = fmaxf(nb[idx], 0.0f);
            float ness = (float)exp(-(double)nv);  // correctly-rounded f32 exp
            key = ((u64)__float_as_uint(ness) << 32) | (u32)(~idx);
        }
        keys[i] = key;
    }
    __syncthreads();
    // bitonic sort, descending (4096 elements)
    for (u32 k = 2; k <= TOPK_CAP; k <<= 1) {
        for (u32 j = k >> 1; j > 0; j >>= 1) {
            for (u32 i = (u32)t; i < TOPK_CAP; i += blockDim.x) {
                u32 ixj = i ^ j;
                if (ixj > i) {
                    u64 a = keys[i], c = keys[ixj];
                    bool desc = ((i & k) == 0);
                    bool sw = desc ? (a < c) : (a > c);
                    if (sw) { keys[i] = c; keys[ixj] = a; }
                }
            }
            __syncthreads();
        }
    }
    const float* s = score + (size_t)b * NPIX;
    for (int i = t; i < NK; i += blockDim.x) {
        u64 key = keys[i];
        u32 idx = ~(u32)key;
        int y = (int)(idx / W), x = (int)(idx % W);
        int yc = min(max(y, 1), H - 2), xc = min(max(x, 1), W - 2);
        int p = yc * W + xc;
        float s00 = s[p], sp0 = s[p + W], sm0 = s[p - W], s0p = s[p + 1], s0m = s[p - 1];
        float spp = s[p + W + 1], spm = s[p + W - 1], smp = s[p - W + 1], smm = s[p - W - 1];
        float gy = 0.5f * (sp0 - sm0);
        float gx = 0.5f * (s0p - s0m);
        float hyy = sp0 - 2.0f * s00 + sm0;
        float hxx = s0p - 2.0f * s00 + s0m;
        float hxy = 0.25f * (spp - spm - smp + smm);
        float det = hyy * hxx - hxy * hxy;
        bool sing = fabsf(det) > 1e-12f;
        float sd = sing ? det : 1.0f;
        float iy = -(hxx * gy - hxy * gx) / sd;
        float ix = -(hyy * gx - hxy * gy) / sd;
        if (!sing) { iy = 0.0f; ix = 0.0f; }
        iy = fminf(fmaxf(iy, -0.5f), 0.5f);
        ix = fminf(fmaxf(ix, -0.5f), 0.5f);
        size_t o = ((size_t)b * NK + (size_t)i) * 3;
        out[o] = (float)y + 0.5f + iy;
        out[o + 1] = (float)x + 0.5f + ix;
        out[o + 2] = fmaxf(nb[idx], 0.0f);
    }
}

extern "C" void kernel_launch(void* const* d_in, const int* in_sizes, int n_in,
                              void* d_out, int out_size, void* d_ws, size_t ws_size,
                              hipStream_t stream) {
    const float* neur = (const float*)d_in[0];
    const float* score = (const float*)d_in[1];
    float* out = (float*)d_out;
    char* ws = (char*)d_ws;
    u32* krem = (u32*)(ws + OFF_KREM);
    u32* prefix = (u32*)(ws + OFF_PREFIX);
    u32* tcount = (u32*)(ws + OFF_TCOUNT);
    u32* hist = (u32*)(ws + OFF_HIST);
    u32* segcnt = (u32*)(ws + OFF_SEGCNT);
    u32* topkidx = (u32*)(ws + OFF_TOPK);
    u32* candf = (u32*)(ws + OFF_CANDF);

    size_t avail = ws_size > OFF_CANDF ? ws_size - OFF_CANDF : 0;
    long long cap_ll = (long long)(avail / (8ull * B * NSEG));
    int seg_cap = cap_ll > SEG_CAP_MAX ? SEG_CAP_MAX : (int)cap_ll;
    u32* candi = candf + (size_t)B * NSEG * seg_cap;

    init_k<<<16, 256, 0, stream>>>(krem, prefix, tcount, hist, segcnt);
    cand_k<<<dim3(W / 256, H - 2 * BORDER, B), 256, 0, stream>>>(neur, score, candf, candi, segcnt, seg_cap);
    for (int shift = 24; shift >= 0; shift -= 8) {
        hist_k<<<dim3(32, B), 256, 0, stream>>>(candf, segcnt, prefix, hist, shift, seg_cap);
        scan_k<<<1, 256, 0, stream>>>(hist, prefix, krem, shift);
    }
    compact_k<<<dim3(32, B), 256, 0, stream>>>(candf, candi, segcnt, prefix, topkidx, tcount, seg_cap);
    final_k<<<B, 1024, 0, stream>>>(neur, score, topkidx, tcount, out);
}

// Round 3
// 269.885 us; speedup vs baseline: 9.7365x; 1.7660x over previous
//
#include <hip/hip_runtime.h>
#include <math.h>

typedef unsigned int u32;
typedef unsigned long long u64;

#define B 8
#define H 1024
#define W 1536
#define NPIX (H * W)
#define NK 2048
#define BORDER 16
#define NSEG 64
#define TY 8
#define NTILE 6            // W / 256
#define GRIDY 31           // 992 rows / (TY * 4 waves)
#define HBINS 512
#define TOPK_CAP 4096
#define SEG_CAP_MAX 4096
#define CTR_PAD 32
#define IDX_MASK 0x1FFFFFu

// workspace layout (bytes)
#define OFF_PREFIX 0        // u32[B]
#define OFF_TCOUNT 128      // u32[B*CTR_PAD]
#define OFF_HIST   4096     // u32[B*HBINS]
#define OFF_SEGCNT 20480    // u32[B*NSEG*CTR_PAD]
#define OFF_TOPK   86016    // u32[B*TOPK_CAP]
#define OFF_CAND   217088   // u32[B*NSEG*seg_cap]

__global__ void init_k(u32* tcount, u32* hist, u32* segcnt) {
    u32 t = blockIdx.x * blockDim.x + threadIdx.x;
    u32 stride = gridDim.x * blockDim.x;
    for (u32 i = t; i < B * CTR_PAD; i += stride) tcount[i] = 0;
    for (u32 i = t; i < B * HBINS; i += stride) hist[i] = 0;
    for (u32 i = t; i < B * NSEG * CTR_PAD; i += stride) segcnt[i] = 0;
}

__global__ __launch_bounds__(256) void cand_k(const float* __restrict__ neur,
                                              const float* __restrict__ score,
                                              u32* __restrict__ candp,
                                              u32* __restrict__ segcnt,
                                              u32* __restrict__ hist, int seg_cap) {
    __shared__ u32 lh[HBINS];
    int tile = blockIdx.x;
    int b = blockIdx.z;
    int wave = threadIdx.x >> 6;
    int lane = threadIdx.x & 63;
    for (int i = threadIdx.x; i < HBINS; i += 256) lh[i] = 0;
    __syncthreads();

    int strip = blockIdx.y * 4 + wave;
    int y0 = BORDER + strip * TY;
    int x0 = tile * 256 + lane * 4;
    const float* s = score + (size_t)b * NPIX;
    const float* nb = neur + (size_t)b * NPIX;
    bool haveL = (tile > 0) && (lane == 0);
    bool haveR = (tile < NTILE - 1) && (lane == 63);

    float4 c0, cp, hm, h0, hp;
    {
        const float* row = s + (size_t)(y0 - 1) * W + x0;
        float4 c = *(const float4*)row;
        float l = __shfl_up(c.w, 1); if (haveL) l = row[-1];
        float r = __shfl_down(c.x, 1); if (haveR) r = row[4];
        hm.x = fmaxf(fmaxf(l, c.x), c.y);
        hm.y = fmaxf(fmaxf(c.x, c.y), c.z);
        hm.z = fmaxf(fmaxf(c.y, c.z), c.w);
        hm.w = fmaxf(fmaxf(c.z, c.w), r);
    }
    {
        const float* row = s + (size_t)y0 * W + x0;
        c0 = *(const float4*)row;
        float l = __shfl_up(c0.w, 1); if (haveL) l = row[-1];
        float r = __shfl_down(c0.x, 1); if (haveR) r = row[4];
        h0.x = fmaxf(fmaxf(l, c0.x), c0.y);
        h0.y = fmaxf(fmaxf(c0.x, c0.y), c0.z);
        h0.z = fmaxf(fmaxf(c0.y, c0.z), c0.w);
        h0.w = fmaxf(fmaxf(c0.z, c0.w), r);
    }
    for (int ys = 0; ys < TY; ++ys) {
        int y = y0 + ys;
        {
            const float* row = s + (size_t)(y + 1) * W + x0;
            cp = *(const float4*)row;
            float l = __shfl_up(cp.w, 1); if (haveL) l = row[-1];
            float r = __shfl_down(cp.x, 1); if (haveR) r = row[4];
            hp.x = fmaxf(fmaxf(l, cp.x), cp.y);
            hp.y = fmaxf(fmaxf(cp.x, cp.y), cp.z);
            hp.z = fmaxf(fmaxf(cp.y, cp.z), cp.w);
            hp.w = fmaxf(fmaxf(cp.z, cp.w), r);
        }
        float pv[4];
        pv[0] = fmaxf(fmaxf(hm.x, h0.x), hp.x);
        pv[1] = fmaxf(fmaxf(hm.y, h0.y), hp.y);
        pv[2] = fmaxf(fmaxf(hm.z, h0.z), hp.z);
        pv[3] = fmaxf(fmaxf(hm.w, h0.w), hp.w);
        float cv[4] = {c0.x, c0.y, c0.z, c0.w};
        u32 idx0 = (u32)(y * W + x0);
        bool ext[4];
        u32 pk[4] = {0, 0, 0, 0};
        #pragma unroll
        for (int e = 0; e < 4; ++e) {
            int x = x0 + e;
            ext[e] = (x >= BORDER) && (x < W - BORDER) && (cv[e] >= pv[e]);
        }
        u64 mm[4]; u32 pc[4];
        u32 tot = 0;
        #pragma unroll
        for (int e = 0; e < 4; ++e) {
            mm[e] = __ballot((int)ext[e]);
            pc[e] = (u32)__popcll(mm[e]);
            tot += pc[e];
        }
        if (tot) {
            #pragma unroll
            for (int e = 0; e < 4; ++e) {
                if (ext[e]) {
                    u32 idx = idx0 + (u32)e;
                    float nv = fmaxf(nb[idx], 0.0f);
                    u32 fb = __float_as_uint(nv);
                    u32 bin = fb >> 21; if (bin > HBINS - 1) bin = HBINS - 1;
                    pk[e] = (bin << 21) | idx;
                    atomicAdd(&lh[bin], 1u);
                }
            }
            int seg = y & (NSEG - 1);
            u32* ctr = &segcnt[(u32)(b * NSEG + seg) * CTR_PAD];
            u32 base = 0;
            if (lane == 0) base = atomicAdd(ctr, tot);
            base = (u32)__shfl((int)base, 0, 64);
            u64 ltm = (1ull << (u32)lane) - 1ull;
            u32 sbase = (u32)(b * NSEG + seg) * (u32)seg_cap;
            #pragma unroll
            for (int e = 0; e < 4; ++e) {
                if (ext[e]) {
                    u32 pos = base + (u32)__popcll(mm[e] & ltm);
                    if ((int)pos < seg_cap) candp[sbase + pos] = pk[e];
                }
                base += pc[e];
            }
        }
        hm = h0; h0 = hp; c0 = cp;
    }
    __syncthreads();
    for (int i = threadIdx.x; i < HBINS; i += 256) {
        u32 v = lh[i];
        if (v) atomicAdd(&hist[(u32)b * HBINS + i], v);
    }
}

__global__ __launch_bounds__(512) void scan_k(const u32* __restrict__ hist,
                                              u32* __restrict__ prefix) {
    __shared__ u32 cs[HBINS];
    int b = blockIdx.x;
    int t = threadIdx.x;
    cs[t] = hist[(u32)b * HBINS + t];
    __syncthreads();
    for (int off = 1; off < HBINS; off <<= 1) {
        u32 a = (t >= off) ? cs[t - off] : 0;
        __syncthreads();
        cs[t] += a;
        __syncthreads();
    }
    u32 before = (t == 0) ? 0u : cs[t - 1];
    if (before < NK && cs[t] >= NK) {
        // include bins <= t+1 entirely: packed < (t+2)<<21
        prefix[b] = ((u32)t + 2u) << 21;
    }
}

__global__ void compact_k(const u32* __restrict__ candp, const u32* __restrict__ segcnt,
                          const u32* __restrict__ prefix, u32* __restrict__ topkidx,
                          u32* tcount, int seg_cap) {
    int b = blockIdx.y;
    u32 piv = prefix[b];
    u32 t0 = blockIdx.x * blockDim.x + threadIdx.x;
    u32 stride = gridDim.x * blockDim.x;
    int lane = threadIdx.x & 63;
    for (int seg = 0; seg < NSEG; ++seg) {
        u32 cnt = segcnt[(u32)(b * NSEG + seg) * CTR_PAD];
        if ((int)cnt > seg_cap) cnt = (u32)seg_cap;
        u32 base = (u32)(b * NSEG + seg) * (u32)seg_cap;
        u32 iters = (cnt + stride - 1) / stride;
        for (u32 it = 0; it < iters; ++it) {
            u32 i = it * stride + t0;
            bool f = false;
            u32 idx = 0;
            if (i < cnt) {
                u32 p = candp[base + i];
                f = (p < piv);
                idx = p & IDX_MASK;
            }
            u64 m = __ballot((int)f);
            if (m) {
                int leader = __ffsll((long long)m) - 1;
                u32 wbase = 0;
                if (lane == leader) wbase = atomicAdd(&tcount[b * CTR_PAD], (u32)__popcll(m));
                wbase = (u32)__shfl((int)wbase, leader, 64);
                if (f) {
                    u32 pos = wbase + (u32)__popcll(m & ((1ull << (u32)lane) - 1ull));
                    if (pos < TOPK_CAP) topkidx[(u32)b * TOPK_CAP + pos] = idx;
                }
            }
        }
    }
}

__global__ __launch_bounds__(1024) void final_k(const float* __restrict__ neur,
                                                const float* __restrict__ score,
                                                const u32* __restrict__ topkidx,
                                                const u32* __restrict__ tcount,
                                                float* __restrict__ out) {
    __shared__ u64 keys[TOPK_CAP];
    int b = blockIdx.x;
    int t = threadIdx.x;
    u32 cnt = tcount[b * CTR_PAD];
    if (cnt > TOPK_CAP) cnt = TOPK_CAP;
    const float* nb = neur + (size_t)b * NPIX;
    for (u32 i = (u32)t; i < TOPK_CAP; i += blockDim.x) {
        u64 key = 0;
        if (i < cnt) {
            u32 idx = topkidx[(u32)b * TOPK_CAP + i];
            float nv = fmaxf(nb[idx], 0.0f);
            float ness = (float)exp(-(double)nv);  // correctly-rounded f32 exp
            key = ((u64)__float_as_uint(ness) << 32) | (u32)(~idx);
        }
        keys[i] = key;
    }
    __syncthreads();
    for (u32 k = 2; k <= TOPK_CAP; k <<= 1) {
        for (u32 j = k >> 1; j > 0; j >>= 1) {
            for (u32 i = (u32)t; i < TOPK_CAP; i += blockDim.x) {
                u32 ixj = i ^ j;
                if (ixj > i) {
                    u64 a = keys[i], c = keys[ixj];
                    bool desc = ((i & k) == 0);
                    bool sw = desc ? (a < c) : (a > c);
                    if (sw) { keys[i] = c; keys[ixj] = a; }
                }
            }
            __syncthreads();
        }
    }
    const float* s = score + (size_t)b * NPIX;
    for (int i = t; i < NK; i += blockDim.x) {
        u64 key = keys[i];
        u32 idx = ~(u32)key;
        int y = (int)(idx / W), x = (int)(idx % W);
        int yc = min(max(y, 1), H - 2), xc = min(max(x, 1), W - 2);
        int p = yc * W + xc;
        float s00 = s[p], sp0 = s[p + W], sm0 = s[p - W], s0p = s[p + 1], s0m = s[p - 1];
        float spp = s[p + W + 1], spm = s[p + W - 1], smp = s[p - W + 1], smm = s[p - W - 1];
        float gy = 0.5f * (sp0 - sm0);
        float gx = 0.5f * (s0p - s0m);
        float hyy = sp0 - 2.0f * s00 + sm0;
        float hxx = s0p - 2.0f * s00 + s0m;
        float hxy = 0.25f * (spp - spm - smp + smm);
        float det = hyy * hxx - hxy * hxy;
        bool sing = fabsf(det) > 1e-12f;
        float sd = sing ? det : 1.0f;
        float iy = -(hxx * gy - hxy * gx) / sd;
        float ix = -(hyy * gx - hxy * gy) / sd;
        if (!sing) { iy = 0.0f; ix = 0.0f; }
        iy = fminf(fmaxf(iy, -0.5f), 0.5f);
        ix = fminf(fmaxf(ix, -0.5f), 0.5f);
        size_t o = ((size_t)b * NK + (size_t)i) * 3;
        out[o] = (float)y + 0.5f + iy;
        out[o + 1] = (float)x + 0.5f + ix;
        out[o + 2] = fmaxf(nb[idx], 0.0f);
    }
}

extern "C" void kernel_launch(void* const* d_in, const int* in_sizes, int n_in,
                              void* d_out, int out_size, void* d_ws, size_t ws_size,
                              hipStream_t stream) {
    const float* neur = (const float*)d_in[0];
    const float* score = (const float*)d_in[1];
    float* out = (float*)d_out;
    char* ws = (char*)d_ws;
    u32* prefix = (u32*)(ws + OFF_PREFIX);
    u32* tcount = (u32*)(ws + OFF_TCOUNT);
    u32* hist = (u32*)(ws + OFF_HIST);
    u32* segcnt = (u32*)(ws + OFF_SEGCNT);
    u32* topkidx = (u32*)(ws + OFF_TOPK);
    u32* candp = (u32*)(ws + OFF_CAND);

    size_t avail = ws_size > OFF_CAND ? ws_size - OFF_CAND : 0;
    long long cap_ll = (long long)(avail / (4ull * B * NSEG));
    int seg_cap = cap_ll > SEG_CAP_MAX ? SEG_CAP_MAX : (int)cap_ll;

    init_k<<<16, 256, 0, stream>>>(tcount, hist, segcnt);
    cand_k<<<dim3(NTILE, GRIDY, B), 256, 0, stream>>>(neur, score, candp, segcnt, hist, seg_cap);
    scan_k<<<B, HBINS, 0, stream>>>(hist, prefix);
    compact_k<<<dim3(32, B), 256, 0, stream>>>(candp, segcnt, prefix, topkidx, tcount, seg_cap);
    final_k<<<B, 1024, 0, stream>>>(neur, score, topkidx, tcount, out);
}

// Round 4
// 235.941 us; speedup vs baseline: 11.1373x; 1.1439x over previous
//
#include <hip/hip_runtime.h>
#include <math.h>

typedef unsigned int u32;
typedef unsigned long long u64;

#define B 8
#define H 1024
#define W 1536
#define NPIX (H * W)
#define NK 2048
#define BORDER 16
#define NSEG 64
#define TY 8
#define NTILE 6            // W / 256
#define GRIDY 31           // 992 rows / (TY * 4 waves)
#define HBINS 512
#define TOPK_CAP 4096
#define SORT_N 4096
#define SORT_T 512
#define SEG_CAP_MAX 4096
#define CTR_PAD 32
#define IDX_MASK 0x1FFFFFu

// workspace layout (bytes)
#define OFF_PREFIX 0        // u32[B]
#define OFF_TCOUNT 128      // u32[B*CTR_PAD]
#define OFF_HIST   4096     // u32[B*HBINS]
#define OFF_SEGCNT 20480    // u32[B*NSEG*CTR_PAD]
#define OFF_TOPK   86016    // u32[B*TOPK_CAP]
#define OFF_CAND   217088   // u32[B*NSEG*seg_cap]

__global__ void init_k(u32* tcount, u32* hist, u32* segcnt) {
    u32 t = blockIdx.x * blockDim.x + threadIdx.x;
    u32 stride = gridDim.x * blockDim.x;
    for (u32 i = t; i < B * CTR_PAD; i += stride) tcount[i] = 0;
    for (u32 i = t; i < B * HBINS; i += stride) hist[i] = 0;
    for (u32 i = t; i < B * NSEG * CTR_PAD; i += stride) segcnt[i] = 0;
}

__global__ __launch_bounds__(256) void cand_k(const float* __restrict__ neur,
                                              const float* __restrict__ score,
                                              u32* __restrict__ candp,
                                              u32* __restrict__ segcnt,
                                              u32* __restrict__ hist, int seg_cap) {
    __shared__ u32 lh[HBINS];
    int tile = blockIdx.x;
    int b = blockIdx.z;
    int wave = threadIdx.x >> 6;
    int lane = threadIdx.x & 63;
    for (int i = threadIdx.x; i < HBINS; i += 256) lh[i] = 0;
    __syncthreads();

    int strip = blockIdx.y * 4 + wave;
    int y0 = BORDER + strip * TY;
    int x0 = tile * 256 + lane * 4;
    const float* s = score + (size_t)b * NPIX;
    const float* nb = neur + (size_t)b * NPIX;
    bool haveL = (tile > 0) && (lane == 0);
    bool haveR = (tile < NTILE - 1) && (lane == 63);

    float4 c0, cp, hm, h0, hp;
    {
        const float* row = s + (size_t)(y0 - 1) * W + x0;
        float4 c = *(const float4*)row;
        float l = __shfl_up(c.w, 1); if (haveL) l = row[-1];
        float r = __shfl_down(c.x, 1); if (haveR) r = row[4];
        hm.x = fmaxf(fmaxf(l, c.x), c.y);
        hm.y = fmaxf(fmaxf(c.x, c.y), c.z);
        hm.z = fmaxf(fmaxf(c.y, c.z), c.w);
        hm.w = fmaxf(fmaxf(c.z, c.w), r);
    }
    {
        const float* row = s + (size_t)y0 * W + x0;
        c0 = *(const float4*)row;
        float l = __shfl_up(c0.w, 1); if (haveL) l = row[-1];
        float r = __shfl_down(c0.x, 1); if (haveR) r = row[4];
        h0.x = fmaxf(fmaxf(l, c0.x), c0.y);
        h0.y = fmaxf(fmaxf(c0.x, c0.y), c0.z);
        h0.z = fmaxf(fmaxf(c0.y, c0.z), c0.w);
        h0.w = fmaxf(fmaxf(c0.z, c0.w), r);
    }
    for (int ys = 0; ys < TY; ++ys) {
        int y = y0 + ys;
        {
            const float* row = s + (size_t)(y + 1) * W + x0;
            cp = *(const float4*)row;
            float l = __shfl_up(cp.w, 1); if (haveL) l = row[-1];
            float r = __shfl_down(cp.x, 1); if (haveR) r = row[4];
            hp.x = fmaxf(fmaxf(l, cp.x), cp.y);
            hp.y = fmaxf(fmaxf(cp.x, cp.y), cp.z);
            hp.z = fmaxf(fmaxf(cp.y, cp.z), cp.w);
            hp.w = fmaxf(fmaxf(cp.z, cp.w), r);
        }
        float pv[4];
        pv[0] = fmaxf(fmaxf(hm.x, h0.x), hp.x);
        pv[1] = fmaxf(fmaxf(hm.y, h0.y), hp.y);
        pv[2] = fmaxf(fmaxf(hm.z, h0.z), hp.z);
        pv[3] = fmaxf(fmaxf(hm.w, h0.w), hp.w);
        float cv[4] = {c0.x, c0.y, c0.z, c0.w};
        u32 idx0 = (u32)(y * W + x0);
        bool ext[4];
        u32 pk[4] = {0, 0, 0, 0};
        #pragma unroll
        for (int e = 0; e < 4; ++e) {
            int x = x0 + e;
            ext[e] = (x >= BORDER) && (x < W - BORDER) && (cv[e] >= pv[e]);
        }
        u64 mm[4]; u32 pc[4];
        u32 tot = 0;
        #pragma unroll
        for (int e = 0; e < 4; ++e) {
            mm[e] = __ballot((int)ext[e]);
            pc[e] = (u32)__popcll(mm[e]);
            tot += pc[e];
        }
        if (tot) {
            #pragma unroll
            for (int e = 0; e < 4; ++e) {
                if (ext[e]) {
                    u32 idx = idx0 + (u32)e;
                    float nv = fmaxf(nb[idx], 0.0f);
                    u32 fb = __float_as_uint(nv);
                    u32 bin = fb >> 21; if (bin > HBINS - 1) bin = HBINS - 1;
                    pk[e] = (bin << 21) | idx;
                    atomicAdd(&lh[bin], 1u);
                }
            }
            int seg = y & (NSEG - 1);
            u32* ctr = &segcnt[(u32)(b * NSEG + seg) * CTR_PAD];
            u32 base = 0;
            if (lane == 0) base = atomicAdd(ctr, tot);
            base = (u32)__shfl((int)base, 0, 64);
            u64 ltm = (1ull << (u32)lane) - 1ull;
            u32 sbase = (u32)(b * NSEG + seg) * (u32)seg_cap;
            #pragma unroll
            for (int e = 0; e < 4; ++e) {
                if (ext[e]) {
                    u32 pos = base + (u32)__popcll(mm[e] & ltm);
                    if ((int)pos < seg_cap) candp[sbase + pos] = pk[e];
                }
                base += pc[e];
            }
        }
        hm = h0; h0 = hp; c0 = cp;
    }
    __syncthreads();
    for (int i = threadIdx.x; i < HBINS; i += 256) {
        u32 v = lh[i];
        if (v) atomicAdd(&hist[(u32)b * HBINS + i], v);
    }
}

__global__ __launch_bounds__(512) void scan_k(const u32* __restrict__ hist,
                                              u32* __restrict__ prefix) {
    __shared__ u32 cs[HBINS];
    int b = blockIdx.x;
    int t = threadIdx.x;
    cs[t] = hist[(u32)b * HBINS + t];
    __syncthreads();
    for (int off = 1; off < HBINS; off <<= 1) {
        u32 a = (t >= off) ? cs[t - off] : 0;
        __syncthreads();
        cs[t] += a;
        __syncthreads();
    }
    u32 before = (t == 0) ? 0u : cs[t - 1];
    if (before < NK && cs[t] >= NK) {
        prefix[b] = ((u32)t + 2u) << 21;  // include bins <= t+1 entirely
    }
}

__global__ void compact_k(const u32* __restrict__ candp, const u32* __restrict__ segcnt,
                          const u32* __restrict__ prefix, u32* __restrict__ topkidx,
                          u32* tcount, int seg_cap) {
    int b = blockIdx.y;
    u32 piv = prefix[b];
    u32 t0 = blockIdx.x * blockDim.x + threadIdx.x;
    u32 stride = gridDim.x * blockDim.x;
    int lane = threadIdx.x & 63;
    for (int seg = 0; seg < NSEG; ++seg) {
        u32 cnt = segcnt[(u32)(b * NSEG + seg) * CTR_PAD];
        if ((int)cnt > seg_cap) cnt = (u32)seg_cap;
        u32 base = (u32)(b * NSEG + seg) * (u32)seg_cap;
        u32 iters = (cnt + stride - 1) / stride;
        for (u32 it = 0; it < iters; ++it) {
            u32 i = it * stride + t0;
            bool f = false;
            u32 idx = 0;
            if (i < cnt) {
                u32 p = candp[base + i];
                f = (p < piv);
                idx = p & IDX_MASK;
            }
            u64 m = __ballot((int)f);
            if (m) {
                int leader = __ffsll((long long)m) - 1;
                u32 wbase = 0;
                if (lane == leader) wbase = atomicAdd(&tcount[b * CTR_PAD], (u32)__popcll(m));
                wbase = (u32)__shfl((int)wbase, leader, 64);
                if (f) {
                    u32 pos = wbase + (u32)__popcll(m & ((1ull << (u32)lane) - 1ull));
                    if (pos < TOPK_CAP) topkidx[(u32)b * TOPK_CAP + pos] = idx;
                }
            }
        }
    }
}

// swizzled LDS slot: breaks stride-2^k u64 bank conflicts
__device__ __forceinline__ u32 sw(u32 i) { return i + (i >> 5); }

__device__ __forceinline__ void cex(u64& a, u64& b, bool desc) {
    bool swp = desc ? (a < b) : (a > b);
    if (swp) { u64 tmp = a; a = b; b = tmp; }
}

__global__ __launch_bounds__(SORT_T) void final_k(const float* __restrict__ neur,
                                                  const float* __restrict__ score,
                                                  const u32* __restrict__ topkidx,
                                                  const u32* __restrict__ tcount,
                                                  float* __restrict__ out) {
    __shared__ u64 keys[SORT_N + (SORT_N >> 5)];
    int b = blockIdx.x;
    u32 t = threadIdx.x;
    u32 cnt = tcount[b * CTR_PAD];
    if (cnt > TOPK_CAP) cnt = TOPK_CAP;
    const float* nb = neur + (size_t)b * NPIX;
    for (u32 i = t; i < SORT_N; i += SORT_T) {
        u64 key = 0;
        if (i < cnt) {
            u32 idx = topkidx[(u32)b * TOPK_CAP + i];
            float nv = fmaxf(nb[idx], 0.0f);
            float ness = (float)exp(-(double)nv);  // correctly-rounded f32 exp
            key = ((u64)__float_as_uint(ness) << 32) | (u32)(~idx);
        }
        keys[sw(i)] = key;
    }
    __syncthreads();

    // local phase: k=2,4,8 exact network on contiguous 8-blocks
    {
        u64 r[8];
        u32 base = t * 8u;
        #pragma unroll
        for (int e = 0; e < 8; ++e) r[e] = keys[sw(base + e)];
        // k=2, j=1
        cex(r[0], r[1], true);  cex(r[2], r[3], false);
        cex(r[4], r[5], true);  cex(r[6], r[7], false);
        // k=4, j=2
        cex(r[0], r[2], true);  cex(r[1], r[3], true);
        cex(r[4], r[6], false); cex(r[5], r[7], false);
        // k=4, j=1
        cex(r[0], r[1], true);  cex(r[2], r[3], true);
        cex(r[4], r[5], false); cex(r[6], r[7], false);
        // k=8, j=4,2,1 (uniform dir per block)
        bool d = ((base & 8u) == 0u);
        cex(r[0], r[4], d); cex(r[1], r[5], d); cex(r[2], r[6], d); cex(r[3], r[7], d);
        cex(r[0], r[2], d); cex(r[1], r[3], d); cex(r[4], r[6], d); cex(r[5], r[7], d);
        cex(r[0], r[1], d); cex(r[2], r[3], d); cex(r[4], r[5], d); cex(r[6], r[7], d);
        #pragma unroll
        for (int e = 0; e < 8; ++e) keys[sw(base + e)] = r[e];
    }
    __syncthreads();

    for (u32 k = 16; k <= SORT_N; k <<= 1) {
        u32 j = k >> 1;
        while (j >= 4) {
            // fused stages (4*j0, 2*j0, j0), 8 elements per thread at stride j0
            u32 j0 = j >> 2;
            u32 base = ((t & ~(j0 - 1u)) << 3) | (t & (j0 - 1u));
            bool d = ((base & k) == 0u);
            u64 r[8];
            #pragma unroll
            for (int e = 0; e < 8; ++e) r[e] = keys[sw(base + (u32)e * j0)];
            cex(r[0], r[4], d); cex(r[1], r[5], d); cex(r[2], r[6], d); cex(r[3], r[7], d);
            cex(r[0], r[2], d); cex(r[1], r[3], d); cex(r[4], r[6], d); cex(r[5], r[7], d);
            cex(r[0], r[1], d); cex(r[2], r[3], d); cex(r[4], r[5], d); cex(r[6], r[7], d);
            #pragma unroll
            for (int e = 0; e < 8; ++e) keys[sw(base + (u32)e * j0)] = r[e];
            __syncthreads();
            j >>= 3;
        }
        if (j == 2) {
            // fused stages (2,1): 4 contiguous elements, 2 subgroups/thread
            #pragma unroll
            for (u32 m = 0; m < 2; ++m) {
                u32 vt = t + m * SORT_T;
                u32 base = vt << 2;
                bool d = ((base & k) == 0u);
                u64 r0 = keys[sw(base)], r1 = keys[sw(base + 1)];
                u64 r2 = keys[sw(base + 2)], r3 = keys[sw(base + 3)];
                cex(r0, r2, d); cex(r1, r3, d);
                cex(r0, r1, d); cex(r2, r3, d);
                keys[sw(base)] = r0; keys[sw(base + 1)] = r1;
                keys[sw(base + 2)] = r2; keys[sw(base + 3)] = r3;
            }
            __syncthreads();
        } else if (j == 1) {
            // single stage j=1: 4 pairs per thread
            #pragma unroll
            for (u32 m = 0; m < 4; ++m) {
                u32 vt = t + m * SORT_T;
                u32 base = vt << 1;
                bool d = ((base & k) == 0u);
                u64 r0 = keys[sw(base)], r1 = keys[sw(base + 1)];
                cex(r0, r1, d);
                keys[sw(base)] = r0; keys[sw(base + 1)] = r1;
            }
            __syncthreads();
        }
    }

    const float* s = score + (size_t)b * NPIX;
    for (u32 i = t; i < NK; i += SORT_T) {
        u64 key = keys[sw(i)];
        u32 idx = ~(u32)key;
        int y = (int)(idx / W), x = (int)(idx % W);
        int yc = min(max(y, 1), H - 2), xc = min(max(x, 1), W - 2);
        int p = yc * W + xc;
        float s00 = s[p], sp0 = s[p + W], sm0 = s[p - W], s0p = s[p + 1], s0m = s[p - 1];
        float spp = s[p + W + 1], spm = s[p + W - 1], smp = s[p - W + 1], smm = s[p - W - 1];
        float gy = 0.5f * (sp0 - sm0);
        float gx = 0.5f * (s0p - s0m);
        float hyy = sp0 - 2.0f * s00 + sm0;
        float hxx = s0p - 2.0f * s00 + s0m;
        float hxy = 0.25f * (spp - spm - smp + smm);
        float det = hyy * hxx - hxy * hxy;
        bool sing = fabsf(det) > 1e-12f;
        float sd = sing ? det : 1.0f;
        float iy = -(hxx * gy - hxy * gx) / sd;
        float ix = -(hyy * gx - hxy * gy) / sd;
        if (!sing) { iy = 0.0f; ix = 0.0f; }
        iy = fminf(fmaxf(iy, -0.5f), 0.5f);
        ix = fminf(fmaxf(ix, -0.5f), 0.5f);
        size_t o = ((size_t)b * NK + (size_t)i) * 3;
        out[o] = (float)y + 0.5f + iy;
        out[o + 1] = (float)x + 0.5f + ix;
        out[o + 2] = fmaxf(nb[idx], 0.0f);
    }
}

extern "C" void kernel_launch(void* const* d_in, const int* in_sizes, int n_in,
                              void* d_out, int out_size, void* d_ws, size_t ws_size,
                              hipStream_t stream) {
    const float* neur = (const float*)d_in[0];
    const float* score = (const float*)d_in[1];
    float* out = (float*)d_out;
    char* ws = (char*)d_ws;
    u32* prefix = (u32*)(ws + OFF_PREFIX);
    u32* tcount = (u32*)(ws + OFF_TCOUNT);
    u32* hist = (u32*)(ws + OFF_HIST);
    u32* segcnt = (u32*)(ws + OFF_SEGCNT);
    u32* topkidx = (u32*)(ws + OFF_TOPK);
    u32* candp = (u32*)(ws + OFF_CAND);

    size_t avail = ws_size > OFF_CAND ? ws_size - OFF_CAND : 0;
    long long cap_ll = (long long)(avail / (4ull * B * NSEG));
    int seg_cap = cap_ll > SEG_CAP_MAX ? SEG_CAP_MAX : (int)cap_ll;

    init_k<<<16, 256, 0, stream>>>(tcount, hist, segcnt);
    cand_k<<<dim3(NTILE, GRIDY, B), 256, 0, stream>>>(neur, score, candp, segcnt, hist, seg_cap);
    scan_k<<<B, HBINS, 0, stream>>>(hist, prefix);
    compact_k<<<dim3(32, B), 256, 0, stream>>>(candp, segcnt, prefix, topkidx, tcount, seg_cap);
    final_k<<<B, SORT_T, 0, stream>>>(neur, score, topkidx, tcount, out);
}

// Round 5
// 207.377 us; speedup vs baseline: 12.6713x; 1.1377x over previous
//
#include <hip/hip_runtime.h>
#include <math.h>

typedef unsigned int u32;
typedef unsigned long long u64;

#define B 8
#define H 1024
#define W 1536
#define NPIX (H * W)
#define NK 2048
#define BORDER 16
#define NSEG 64
#define TY 8
#define NTILE 6            // W / 256
#define GRIDY 31           // 992 rows / (TY * 4 waves)
#define HBINS 512
#define TOPK_CAP 4096
#define SORT_N 4096
#define SORT_T 512
#define SEG_CAP_MAX 4096
#define CTR_PAD 32
#define IDX_MASK 0x1FFFFFu

// workspace layout (bytes)
#define OFF_PREFIX 0        // u32[B]
#define OFF_TCOUNT 128      // u32[B*CTR_PAD]
#define OFF_HIST   4096     // u32[B*HBINS]
#define OFF_SEGCNT 20480    // u32[B*NSEG*CTR_PAD]
#define OFF_TOPK   86016    // u32[B*TOPK_CAP]
#define OFF_CAND   217088   // u32[B*NSEG*seg_cap]

__global__ __launch_bounds__(256) void cand_k(const float* __restrict__ neur,
                                              const float* __restrict__ score,
                                              u32* __restrict__ candp,
                                              u32* __restrict__ segcnt,
                                              u32* __restrict__ hist, int seg_cap) {
    __shared__ u32 lh[HBINS];
    int tile = blockIdx.x;
    int b = blockIdx.z;
    int wave = threadIdx.x >> 6;
    int lane = threadIdx.x & 63;
    for (int i = threadIdx.x; i < HBINS; i += 256) lh[i] = 0;
    __syncthreads();

    int strip = blockIdx.y * 4 + wave;
    int y0 = BORDER + strip * TY;
    int x0 = tile * 256 + lane * 4;
    const float* s = score + (size_t)b * NPIX;
    const float* nb = neur + (size_t)b * NPIX;
    bool haveL = (tile > 0) && (lane == 0);
    bool haveR = (tile < NTILE - 1) && (lane == 63);

    float4 c0, cp, hm, h0, hp;
    {
        const float* row = s + (size_t)(y0 - 1) * W + x0;
        float4 c = *(const float4*)row;
        float l = __shfl_up(c.w, 1); if (haveL) l = row[-1];
        float r = __shfl_down(c.x, 1); if (haveR) r = row[4];
        hm.x = fmaxf(fmaxf(l, c.x), c.y);
        hm.y = fmaxf(fmaxf(c.x, c.y), c.z);
        hm.z = fmaxf(fmaxf(c.y, c.z), c.w);
        hm.w = fmaxf(fmaxf(c.z, c.w), r);
    }
    {
        const float* row = s + (size_t)y0 * W + x0;
        c0 = *(const float4*)row;
        float l = __shfl_up(c0.w, 1); if (haveL) l = row[-1];
        float r = __shfl_down(c0.x, 1); if (haveR) r = row[4];
        h0.x = fmaxf(fmaxf(l, c0.x), c0.y);
        h0.y = fmaxf(fmaxf(c0.x, c0.y), c0.z);
        h0.z = fmaxf(fmaxf(c0.y, c0.z), c0.w);
        h0.w = fmaxf(fmaxf(c0.z, c0.w), r);
    }
    for (int ys = 0; ys < TY; ++ys) {
        int y = y0 + ys;
        {
            const float* row = s + (size_t)(y + 1) * W + x0;
            cp = *(const float4*)row;
            float l = __shfl_up(cp.w, 1); if (haveL) l = row[-1];
            float r = __shfl_down(cp.x, 1); if (haveR) r = row[4];
            hp.x = fmaxf(fmaxf(l, cp.x), cp.y);
            hp.y = fmaxf(fmaxf(cp.x, cp.y), cp.z);
            hp.z = fmaxf(fmaxf(cp.y, cp.z), cp.w);
            hp.w = fmaxf(fmaxf(cp.z, cp.w), r);
        }
        float pv[4];
        pv[0] = fmaxf(fmaxf(hm.x, h0.x), hp.x);
        pv[1] = fmaxf(fmaxf(hm.y, h0.y), hp.y);
        pv[2] = fmaxf(fmaxf(hm.z, h0.z), hp.z);
        pv[3] = fmaxf(fmaxf(hm.w, h0.w), hp.w);
        float cv[4] = {c0.x, c0.y, c0.z, c0.w};
        u32 idx0 = (u32)(y * W + x0);
        bool ext[4];
        u32 pk[4] = {0, 0, 0, 0};
        #pragma unroll
        for (int e = 0; e < 4; ++e) {
            int x = x0 + e;
            ext[e] = (x >= BORDER) && (x < W - BORDER) && (cv[e] >= pv[e]);
        }
        u64 mm[4]; u32 pc[4];
        u32 tot = 0;
        #pragma unroll
        for (int e = 0; e < 4; ++e) {
            mm[e] = __ballot((int)ext[e]);
            pc[e] = (u32)__popcll(mm[e]);
            tot += pc[e];
        }
        if (tot) {
            #pragma unroll
            for (int e = 0; e < 4; ++e) {
                if (ext[e]) {
                    u32 idx = idx0 + (u32)e;
                    float nv = fmaxf(nb[idx], 0.0f);
                    u32 fb = __float_as_uint(nv);
                    u32 bin = fb >> 21; if (bin > HBINS - 1) bin = HBINS - 1;
                    pk[e] = (bin << 21) | idx;
                    atomicAdd(&lh[bin], 1u);
                }
            }
            int seg = y & (NSEG - 1);
            u32* ctr = &segcnt[(u32)(b * NSEG + seg) * CTR_PAD];
            u32 base = 0;
            if (lane == 0) base = atomicAdd(ctr, tot);
            base = (u32)__shfl((int)base, 0, 64);
            u64 ltm = (1ull << (u32)lane) - 1ull;
            u32 sbase = (u32)(b * NSEG + seg) * (u32)seg_cap;
            #pragma unroll
            for (int e = 0; e < 4; ++e) {
                if (ext[e]) {
                    u32 pos = base + (u32)__popcll(mm[e] & ltm);
                    if ((int)pos < seg_cap) candp[sbase + pos] = pk[e];
                }
                base += pc[e];
            }
        }
        hm = h0; h0 = hp; c0 = cp;
    }
    __syncthreads();
    for (int i = threadIdx.x; i < HBINS; i += 256) {
        u32 v = lh[i];
        if (v) atomicAdd(&hist[(u32)b * HBINS + i], v);
    }
}

__global__ __launch_bounds__(512) void scan_k(const u32* __restrict__ hist,
                                              u32* __restrict__ prefix) {
    __shared__ u32 cs[HBINS];
    int b = blockIdx.x;
    int t = threadIdx.x;
    cs[t] = hist[(u32)b * HBINS + t];
    __syncthreads();
    for (int off = 1; off < HBINS; off <<= 1) {
        u32 a = (t >= off) ? cs[t - off] : 0;
        __syncthreads();
        cs[t] += a;
        __syncthreads();
    }
    u32 before = (t == 0) ? 0u : cs[t - 1];
    if (before < NK && cs[t] >= NK) {
        prefix[b] = ((u32)t + 2u) << 21;  // include bins <= t+1 entirely
    }
}

__global__ __launch_bounds__(256) void compact_k(const u32* __restrict__ candp,
                                                 const u32* __restrict__ segcnt,
                                                 const u32* __restrict__ prefix,
                                                 u32* __restrict__ topkidx,
                                                 u32* tcount, int seg_cap) {
    int seg = blockIdx.x;
    int b = blockIdx.y;
    u32 piv = prefix[b];
    int lane = threadIdx.x & 63;
    u32 cnt = segcnt[(u32)(b * NSEG + seg) * CTR_PAD];
    if ((int)cnt > seg_cap) cnt = (u32)seg_cap;
    u32 base = (u32)(b * NSEG + seg) * (u32)seg_cap;
    u32 iters = (cnt + 255u) / 256u;
    for (u32 it = 0; it < iters; ++it) {
        u32 i = it * 256u + threadIdx.x;
        bool f = false;
        u32 idx = 0;
        if (i < cnt) {
            u32 p = candp[base + i];
            f = (p < piv);
            idx = p & IDX_MASK;
        }
        u64 m = __ballot((int)f);
        if (m) {
            int leader = __ffsll((long long)m) - 1;
            u32 wbase = 0;
            if (lane == leader) wbase = atomicAdd(&tcount[b * CTR_PAD], (u32)__popcll(m));
            wbase = (u32)__shfl((int)wbase, leader, 64);
            if (f) {
                u32 pos = wbase + (u32)__popcll(m & ((1ull << (u32)lane) - 1ull));
                if (pos < TOPK_CAP) topkidx[(u32)b * TOPK_CAP + pos] = idx;
            }
        }
    }
}

// swizzled LDS slot: breaks stride-2^k u64 bank conflicts
__device__ __forceinline__ u32 sw(u32 i) { return i + (i >> 5); }

__device__ __forceinline__ void cex(u64& a, u64& b, bool desc) {
    bool swp = desc ? (a < b) : (a > b);
    if (swp) { u64 tmp = a; a = b; b = tmp; }
}

__global__ __launch_bounds__(SORT_T) void final_k(const float* __restrict__ neur,
                                                  const float* __restrict__ score,
                                                  const u32* __restrict__ topkidx,
                                                  const u32* __restrict__ tcount,
                                                  float* __restrict__ out) {
    __shared__ u64 keys[SORT_N + (SORT_N >> 5)];
    int b = blockIdx.x;
    u32 t = threadIdx.x;
    u32 cnt = tcount[b * CTR_PAD];
    if (cnt > TOPK_CAP) cnt = TOPK_CAP;
    const float* nb = neur + (size_t)b * NPIX;
    for (u32 i = t; i < SORT_N; i += SORT_T) {
        u64 key = 0;
        if (i < cnt) {
            u32 idx = topkidx[(u32)b * TOPK_CAP + i];
            float nv = fmaxf(nb[idx], 0.0f);
            float ness = (float)exp(-(double)nv);  // correctly-rounded f32 exp
            key = ((u64)__float_as_uint(ness) << 32) | (u32)(~idx);
        }
        keys[sw(i)] = key;
    }
    __syncthreads();

    // local phase: k=2,4,8 exact network on contiguous 8-blocks
    {
        u64 r[8];
        u32 base = t * 8u;
        #pragma unroll
        for (int e = 0; e < 8; ++e) r[e] = keys[sw(base + e)];
        cex(r[0], r[1], true);  cex(r[2], r[3], false);
        cex(r[4], r[5], true);  cex(r[6], r[7], false);
        cex(r[0], r[2], true);  cex(r[1], r[3], true);
        cex(r[4], r[6], false); cex(r[5], r[7], false);
        cex(r[0], r[1], true);  cex(r[2], r[3], true);
        cex(r[4], r[5], false); cex(r[6], r[7], false);
        bool d = ((base & 8u) == 0u);
        cex(r[0], r[4], d); cex(r[1], r[5], d); cex(r[2], r[6], d); cex(r[3], r[7], d);
        cex(r[0], r[2], d); cex(r[1], r[3], d); cex(r[4], r[6], d); cex(r[5], r[7], d);
        cex(r[0], r[1], d); cex(r[2], r[3], d); cex(r[4], r[5], d); cex(r[6], r[7], d);
        #pragma unroll
        for (int e = 0; e < 8; ++e) keys[sw(base + e)] = r[e];
    }
    __syncthreads();

    for (u32 k = 16; k <= SORT_N; k <<= 1) {
        u32 j = k >> 1;
        while (j >= 4) {
            u32 j0 = j >> 2;
            u32 base = ((t & ~(j0 - 1u)) << 3) | (t & (j0 - 1u));
            bool d = ((base & k) == 0u);
            u64 r[8];
            #pragma unroll
            for (int e = 0; e < 8; ++e) r[e] = keys[sw(base + (u32)e * j0)];
            cex(r[0], r[4], d); cex(r[1], r[5], d); cex(r[2], r[6], d); cex(r[3], r[7], d);
            cex(r[0], r[2], d); cex(r[1], r[3], d); cex(r[4], r[6], d); cex(r[5], r[7], d);
            cex(r[0], r[1], d); cex(r[2], r[3], d); cex(r[4], r[5], d); cex(r[6], r[7], d);
            #pragma unroll
            for (int e = 0; e < 8; ++e) keys[sw(base + (u32)e * j0)] = r[e];
            __syncthreads();
            j >>= 3;
        }
        if (j == 2) {
            #pragma unroll
            for (u32 m = 0; m < 2; ++m) {
                u32 vt = t + m * SORT_T;
                u32 base = vt << 2;
                bool d = ((base & k) == 0u);
                u64 r0 = keys[sw(base)], r1 = keys[sw(base + 1)];
                u64 r2 = keys[sw(base + 2)], r3 = keys[sw(base + 3)];
                cex(r0, r2, d); cex(r1, r3, d);
                cex(r0, r1, d); cex(r2, r3, d);
                keys[sw(base)] = r0; keys[sw(base + 1)] = r1;
                keys[sw(base + 2)] = r2; keys[sw(base + 3)] = r3;
            }
            __syncthreads();
        } else if (j == 1) {
            #pragma unroll
            for (u32 m = 0; m < 4; ++m) {
                u32 vt = t + m * SORT_T;
                u32 base = vt << 1;
                bool d = ((base & k) == 0u);
                u64 r0 = keys[sw(base)], r1 = keys[sw(base + 1)];
                cex(r0, r1, d);
                keys[sw(base)] = r0; keys[sw(base + 1)] = r1;
            }
            __syncthreads();
        }
    }

    const float* s = score + (size_t)b * NPIX;
    for (u32 i = t; i < NK; i += SORT_T) {
        u64 key = keys[sw(i)];
        u32 idx = ~(u32)key;
        int y = (int)(idx / W), x = (int)(idx % W);
        int yc = min(max(y, 1), H - 2), xc = min(max(x, 1), W - 2);
        int p = yc * W + xc;
        float s00 = s[p], sp0 = s[p + W], sm0 = s[p - W], s0p = s[p + 1], s0m = s[p - 1];
        float spp = s[p + W + 1], spm = s[p + W - 1], smp = s[p - W + 1], smm = s[p - W - 1];
        float gy = 0.5f * (sp0 - sm0);
        float gx = 0.5f * (s0p - s0m);
        float hyy = sp0 - 2.0f * s00 + sm0;
        float hxx = s0p - 2.0f * s00 + s0m;
        float hxy = 0.25f * (spp - spm - smp + smm);
        float det = hyy * hxx - hxy * hxy;
        bool sing = fabsf(det) > 1e-12f;
        float sd = sing ? det : 1.0f;
        float iy = -(hxx * gy - hxy * gx) / sd;
        float ix = -(hyy * gx - hxy * gy) / sd;
        if (!sing) { iy = 0.0f; ix = 0.0f; }
        iy = fminf(fmaxf(iy, -0.5f), 0.5f);
        ix = fminf(fmaxf(ix, -0.5f), 0.5f);
        size_t o = ((size_t)b * NK + (size_t)i) * 3;
        out[o] = (float)y + 0.5f + iy;
        out[o + 1] = (float)x + 0.5f + ix;
        out[o + 2] = fmaxf(nb[idx], 0.0f);
    }
}

extern "C" void kernel_launch(void* const* d_in, const int* in_sizes, int n_in,
                              void* d_out, int out_size, void* d_ws, size_t ws_size,
                              hipStream_t stream) {
    const float* neur = (const float*)d_in[0];
    const float* score = (const float*)d_in[1];
    float* out = (float*)d_out;
    char* ws = (char*)d_ws;
    u32* prefix = (u32*)(ws + OFF_PREFIX);
    u32* tcount = (u32*)(ws + OFF_TCOUNT);
    u32* hist = (u32*)(ws + OFF_HIST);
    u32* segcnt = (u32*)(ws + OFF_SEGCNT);
    u32* topkidx = (u32*)(ws + OFF_TOPK);
    u32* candp = (u32*)(ws + OFF_CAND);

    size_t avail = ws_size > OFF_CAND ? ws_size - OFF_CAND : 0;
    long long cap_ll = (long long)(avail / (4ull * B * NSEG));
    int seg_cap = cap_ll > SEG_CAP_MAX ? SEG_CAP_MAX : (int)cap_ll;

    // zero prefix/tcount/hist/segcnt in one memset node (replaces init_k)
    hipMemsetAsync(ws, 0, OFF_TOPK, stream);
    cand_k<<<dim3(NTILE, GRIDY, B), 256, 0, stream>>>(neur, score, candp, segcnt, hist, seg_cap);
    scan_k<<<B, HBINS, 0, stream>>>(hist, prefix);
    compact_k<<<dim3(NSEG, B), 256, 0, stream>>>(candp, segcnt, prefix, topkidx, tcount, seg_cap);
    final_k<<<B, SORT_T, 0, stream>>>(neur, score, topkidx, tcount, out);
}

// Round 6
// 201.491 us; speedup vs baseline: 13.0415x; 1.0292x over previous
//
#include <hip/hip_runtime.h>
#include <math.h>

typedef unsigned int u32;
typedef unsigned long long u64;

#define B 8
#define H 1024
#define W 1536
#define NPIX (H * W)
#define NK 2048
#define BORDER 16
#define NSEG 64
#define TY 8
#define NTILE 6            // W / 256
#define GRIDY 31           // 992 rows / (TY * 4 waves)
#define HBINS 512
#define TOPK_CAP 4096
#define SORT_N 4096
#define SORT_T 512
#define SEG_CAP_MAX 4096
#define CTR_PAD 32
#define IDX_MASK 0x1FFFFFu

// workspace layout (bytes)
#define OFF_TCOUNT 128      // u32[B*CTR_PAD]
#define OFF_HIST   4096     // u32[B*HBINS]
#define OFF_SEGCNT 20480    // u32[B*NSEG*CTR_PAD]
#define OFF_TOPK   86016    // u32[B*TOPK_CAP]
#define OFF_CAND   217088   // u32[B*NSEG*seg_cap]

__global__ __launch_bounds__(256) void cand_k(const float* __restrict__ neur,
                                              const float* __restrict__ score,
                                              u32* __restrict__ candp,
                                              u32* __restrict__ segcnt,
                                              u32* __restrict__ hist, int seg_cap) {
    __shared__ u32 lh[HBINS];
    int tile = blockIdx.x;
    int b = blockIdx.z;
    int wave = threadIdx.x >> 6;
    int lane = threadIdx.x & 63;
    for (int i = threadIdx.x; i < HBINS; i += 256) lh[i] = 0;
    __syncthreads();

    int strip = blockIdx.y * 4 + wave;
    int y0 = BORDER + strip * TY;
    int x0 = tile * 256 + lane * 4;
    const float* s = score + (size_t)b * NPIX;
    const float* nb = neur + (size_t)b * NPIX;
    bool haveL = (tile > 0) && (lane == 0);
    bool haveR = (tile < NTILE - 1) && (lane == 63);

    // preload all TY+2 rows: independent loads, all in flight at once
    float4 rv[TY + 2];
    float le[TY + 2], re[TY + 2];
    const float* base_row = s + (size_t)(y0 - 1) * W + x0;
    #pragma unroll
    for (int r = 0; r < TY + 2; ++r) rv[r] = *(const float4*)(base_row + (size_t)r * W);
    #pragma unroll
    for (int r = 0; r < TY + 2; ++r) {
        le[r] = haveL ? base_row[(size_t)r * W - 1] : 0.0f;
        re[r] = haveR ? base_row[(size_t)r * W + 4] : 0.0f;
    }

    float4 hm, h0, hp;
    #pragma unroll
    for (int r = 0; r < 2; ++r) {
        float4 c = rv[r];
        float l = __shfl_up(c.w, 1); if (haveL) l = le[r];
        float rr = __shfl_down(c.x, 1); if (haveR) rr = re[r];
        float4 hh;
        hh.x = fmaxf(fmaxf(l, c.x), c.y);
        hh.y = fmaxf(fmaxf(c.x, c.y), c.z);
        hh.z = fmaxf(fmaxf(c.y, c.z), c.w);
        hh.w = fmaxf(fmaxf(c.z, c.w), rr);
        if (r == 0) hm = hh; else h0 = hh;
    }

    #pragma unroll
    for (int ys = 0; ys < TY; ++ys) {
        int y = y0 + ys;
        {
            float4 c = rv[ys + 2];
            float l = __shfl_up(c.w, 1); if (haveL) l = le[ys + 2];
            float rr = __shfl_down(c.x, 1); if (haveR) rr = re[ys + 2];
            hp.x = fmaxf(fmaxf(l, c.x), c.y);
            hp.y = fmaxf(fmaxf(c.x, c.y), c.z);
            hp.z = fmaxf(fmaxf(c.y, c.z), c.w);
            hp.w = fmaxf(fmaxf(c.z, c.w), rr);
        }
        float pv[4];
        pv[0] = fmaxf(fmaxf(hm.x, h0.x), hp.x);
        pv[1] = fmaxf(fmaxf(hm.y, h0.y), hp.y);
        pv[2] = fmaxf(fmaxf(hm.z, h0.z), hp.z);
        pv[3] = fmaxf(fmaxf(hm.w, h0.w), hp.w);
        float4 c0 = rv[ys + 1];
        float cv[4] = {c0.x, c0.y, c0.z, c0.w};
        u32 idx0 = (u32)(y * W + x0);
        bool ext[4];
        u32 pk[4] = {0, 0, 0, 0};
        #pragma unroll
        for (int e = 0; e < 4; ++e) {
            int x = x0 + e;
            ext[e] = (x >= BORDER) && (x < W - BORDER) && (cv[e] >= pv[e]);
        }
        u64 mm[4]; u32 pc[4];
        u32 tot = 0;
        #pragma unroll
        for (int e = 0; e < 4; ++e) {
            mm[e] = __ballot((int)ext[e]);
            pc[e] = (u32)__popcll(mm[e]);
            tot += pc[e];
        }
        if (tot) {
            #pragma unroll
            for (int e = 0; e < 4; ++e) {
                if (ext[e]) {
                    u32 idx = idx0 + (u32)e;
                    float nv = fmaxf(nb[idx], 0.0f);
                    u32 fb = __float_as_uint(nv);
                    u32 bin = fb >> 21; if (bin > HBINS - 1) bin = HBINS - 1;
                    pk[e] = (bin << 21) | idx;
                    atomicAdd(&lh[bin], 1u);
                }
            }
            int seg = y & (NSEG - 1);
            u32* ctr = &segcnt[(u32)(b * NSEG + seg) * CTR_PAD];
            u32 base = 0;
            if (lane == 0) base = atomicAdd(ctr, tot);
            base = (u32)__shfl((int)base, 0, 64);
            u64 ltm = (1ull << (u32)lane) - 1ull;
            u32 sbase = (u32)(b * NSEG + seg) * (u32)seg_cap;
            #pragma unroll
            for (int e = 0; e < 4; ++e) {
                if (ext[e]) {
                    u32 pos = base + (u32)__popcll(mm[e] & ltm);
                    if ((int)pos < seg_cap) candp[sbase + pos] = pk[e];
                }
                base += pc[e];
            }
        }
        hm = h0; h0 = hp;
    }
    __syncthreads();
    for (int i = threadIdx.x; i < HBINS; i += 256) {
        u32 v = lh[i];
        if (v) atomicAdd(&hist[(u32)b * HBINS + i], v);
    }
}

__global__ __launch_bounds__(256) void compact_k(const u32* __restrict__ candp,
                                                 const u32* __restrict__ segcnt,
                                                 const u32* __restrict__ hist,
                                                 u32* __restrict__ topkidx,
                                                 u32* tcount, int seg_cap) {
    __shared__ u32 piv_s;
    int seg = blockIdx.x;
    int b = blockIdx.y;
    int lane = threadIdx.x & 63;
    // wave 0: recompute pivot from hist (512 bins, 8/lane + shfl scan)
    if (threadIdx.x < 64) {
        if (threadIdx.x == 0) piv_s = 0xFFFFFFFFu;
        u32 v[8];
        u32 s8 = 0;
        #pragma unroll
        for (int e = 0; e < 8; ++e) {
            v[e] = hist[(u32)b * HBINS + (u32)threadIdx.x * 8u + e];
            s8 += v[e];
        }
        u32 incl = s8;
        #pragma unroll
        for (int off = 1; off < 64; off <<= 1) {
            u32 o = (u32)__shfl_up((int)incl, off, 64);
            if (lane >= off) incl += o;
        }
        u32 excl = incl - s8;
        if (excl < NK && incl >= NK) {
            u32 cum = excl;
            u32 T = 0;
            #pragma unroll
            for (int e = 0; e < 8; ++e) {
                cum += v[e];
                if (cum >= NK) { T = (u32)threadIdx.x * 8u + e; break; }
            }
            piv_s = (T + 2u) << 21;  // include bins <= T+1 entirely
        }
    }
    __syncthreads();
    u32 piv = piv_s;

    u32 cnt = segcnt[(u32)(b * NSEG + seg) * CTR_PAD];
    if ((int)cnt > seg_cap) cnt = (u32)seg_cap;
    u32 base = (u32)(b * NSEG + seg) * (u32)seg_cap;
    u32 iters = (cnt + 255u) / 256u;
    for (u32 it = 0; it < iters; ++it) {
        u32 i = it * 256u + threadIdx.x;
        bool f = false;
        u32 idx = 0;
        if (i < cnt) {
            u32 p = candp[base + i];
            f = (p < piv);
            idx = p & IDX_MASK;
        }
        u64 m = __ballot((int)f);
        if (m) {
            int leader = __ffsll((long long)m) - 1;
            u32 wbase = 0;
            if (lane == leader) wbase = atomicAdd(&tcount[b * CTR_PAD], (u32)__popcll(m));
            wbase = (u32)__shfl((int)wbase, leader, 64);
            if (f) {
                u32 pos = wbase + (u32)__popcll(m & ((1ull << (u32)lane) - 1ull));
                if (pos < TOPK_CAP) topkidx[(u32)b * TOPK_CAP + pos] = idx;
            }
        }
    }
}

// swizzled LDS slot: breaks stride-2^k u64 bank conflicts
__device__ __forceinline__ u32 sw(u32 i) { return i + (i >> 5); }

__device__ __forceinline__ void cex(u64& a, u64& b, bool desc) {
    bool swp = desc ? (a < b) : (a > b);
    if (swp) { u64 tmp = a; a = b; b = tmp; }
}

__global__ __launch_bounds__(SORT_T) void final_k(const float* __restrict__ neur,
                                                  const float* __restrict__ score,
                                                  const u32* __restrict__ topkidx,
                                                  const u32* __restrict__ tcount,
                                                  float* __restrict__ out) {
    __shared__ u64 keys[SORT_N + (SORT_N >> 5)];
    int b = blockIdx.x;
    u32 t = threadIdx.x;
    u32 cnt = tcount[b * CTR_PAD];
    if (cnt > TOPK_CAP) cnt = TOPK_CAP;
    const float* nb = neur + (size_t)b * NPIX;
    for (u32 i = t; i < SORT_N; i += SORT_T) {
        u64 key = 0;
        if (i < cnt) {
            u32 idx = topkidx[(u32)b * TOPK_CAP + i];
            float nv = fmaxf(nb[idx], 0.0f);
            float ness = (float)exp(-(double)nv);  // correctly-rounded f32 exp
            key = ((u64)__float_as_uint(ness) << 32) | (u32)(~idx);
        }
        keys[sw(i)] = key;
    }
    __syncthreads();

    // local phase: k=2,4,8 exact network on contiguous 8-blocks
    {
        u64 r[8];
        u32 base = t * 8u;
        #pragma unroll
        for (int e = 0; e < 8; ++e) r[e] = keys[sw(base + e)];
        cex(r[0], r[1], true);  cex(r[2], r[3], false);
        cex(r[4], r[5], true);  cex(r[6], r[7], false);
        cex(r[0], r[2], true);  cex(r[1], r[3], true);
        cex(r[4], r[6], false); cex(r[5], r[7], false);
        cex(r[0], r[1], true);  cex(r[2], r[3], true);
        cex(r[4], r[5], false); cex(r[6], r[7], false);
        bool d = ((base & 8u) == 0u);
        cex(r[0], r[4], d); cex(r[1], r[5], d); cex(r[2], r[6], d); cex(r[3], r[7], d);
        cex(r[0], r[2], d); cex(r[1], r[3], d); cex(r[4], r[6], d); cex(r[5], r[7], d);
        cex(r[0], r[1], d); cex(r[2], r[3], d); cex(r[4], r[5], d); cex(r[6], r[7], d);
        #pragma unroll
        for (int e = 0; e < 8; ++e) keys[sw(base + e)] = r[e];
    }
    __syncthreads();

    for (u32 k = 16; k <= SORT_N; k <<= 1) {
        u32 j = k >> 1;
        while (j >= 4) {
            u32 j0 = j >> 2;
            u32 base = ((t & ~(j0 - 1u)) << 3) | (t & (j0 - 1u));
            bool d = ((base & k) == 0u);
            u64 r[8];
            #pragma unroll
            for (int e = 0; e < 8; ++e) r[e] = keys[sw(base + (u32)e * j0)];
            cex(r[0], r[4], d); cex(r[1], r[5], d); cex(r[2], r[6], d); cex(r[3], r[7], d);
            cex(r[0], r[2], d); cex(r[1], r[3], d); cex(r[4], r[6], d); cex(r[5], r[7], d);
            cex(r[0], r[1], d); cex(r[2], r[3], d); cex(r[4], r[5], d); cex(r[6], r[7], d);
            #pragma unroll
            for (int e = 0; e < 8; ++e) keys[sw(base + (u32)e * j0)] = r[e];
            __syncthreads();
            j >>= 3;
        }
        if (j == 2) {
            #pragma unroll
            for (u32 m = 0; m < 2; ++m) {
                u32 vt = t + m * SORT_T;
                u32 base = vt << 2;
                bool d = ((base & k) == 0u);
                u64 r0 = keys[sw(base)], r1 = keys[sw(base + 1)];
                u64 r2 = keys[sw(base + 2)], r3 = keys[sw(base + 3)];
                cex(r0, r2, d); cex(r1, r3, d);
                cex(r0, r1, d); cex(r2, r3, d);
                keys[sw(base)] = r0; keys[sw(base + 1)] = r1;
                keys[sw(base + 2)] = r2; keys[sw(base + 3)] = r3;
            }
            __syncthreads();
        } else if (j == 1) {
            #pragma unroll
            for (u32 m = 0; m < 4; ++m) {
                u32 vt = t + m * SORT_T;
                u32 base = vt << 1;
                bool d = ((base & k) == 0u);
                u64 r0 = keys[sw(base)], r1 = keys[sw(base + 1)];
                cex(r0, r1, d);
                keys[sw(base)] = r0; keys[sw(base + 1)] = r1;
            }
            __syncthreads();
        }
    }

    const float* s = score + (size_t)b * NPIX;
    for (u32 i = t; i < NK; i += SORT_T) {
        u64 key = keys[sw(i)];
        u32 idx = ~(u32)key;
        int y = (int)(idx / W), x = (int)(idx % W);
        int yc = min(max(y, 1), H - 2), xc = min(max(x, 1), W - 2);
        int p = yc * W + xc;
        float s00 = s[p], sp0 = s[p + W], sm0 = s[p - W], s0p = s[p + 1], s0m = s[p - 1];
        float spp = s[p + W + 1], spm = s[p + W - 1], smp = s[p - W + 1], smm = s[p - W - 1];
        float gy = 0.5f * (sp0 - sm0);
        float gx = 0.5f * (s0p - s0m);
        float hyy = sp0 - 2.0f * s00 + sm0;
        float hxx = s0p - 2.0f * s00 + s0m;
        float hxy = 0.25f * (spp - spm - smp + smm);
        float det = hyy * hxx - hxy * hxy;
        bool sing = fabsf(det) > 1e-12f;
        float sd = sing ? det : 1.0f;
        float iy = -(hxx * gy - hxy * gx) / sd;
        float ix = -(hyy * gx - hxy * gy) / sd;
        if (!sing) { iy = 0.0f; ix = 0.0f; }
        iy = fminf(fmaxf(iy, -0.5f), 0.5f);
        ix = fminf(fmaxf(ix, -0.5f), 0.5f);
        size_t o = ((size_t)b * NK + (size_t)i) * 3;
        out[o] = (float)y + 0.5f + iy;
        out[o + 1] = (float)x + 0.5f + ix;
        out[o + 2] = fmaxf(nb[idx], 0.0f);
    }
}

extern "C" void kernel_launch(void* const* d_in, const int* in_sizes, int n_in,
                              void* d_out, int out_size, void* d_ws, size_t ws_size,
                              hipStream_t stream) {
    const float* neur = (const float*)d_in[0];
    const float* score = (const float*)d_in[1];
    float* out = (float*)d_out;
    char* ws = (char*)d_ws;
    u32* tcount = (u32*)(ws + OFF_TCOUNT);
    u32* hist = (u32*)(ws + OFF_HIST);
    u32* segcnt = (u32*)(ws + OFF_SEGCNT);
    u32* topkidx = (u32*)(ws + OFF_TOPK);
    u32* candp = (u32*)(ws + OFF_CAND);

    size_t avail = ws_size > OFF_CAND ? ws_size - OFF_CAND : 0;
    long long cap_ll = (long long)(avail / (4ull * B * NSEG));
    int seg_cap = cap_ll > SEG_CAP_MAX ? SEG_CAP_MAX : (int)cap_ll;

    // zero tcount/hist/segcnt in one memset node
    hipMemsetAsync(ws, 0, OFF_TOPK, stream);
    cand_k<<<dim3(NTILE, GRIDY, B), 256, 0, stream>>>(neur, score, candp, segcnt, hist, seg_cap);
    compact_k<<<dim3(NSEG, B), 256, 0, stream>>>(candp, segcnt, hist, topkidx, tcount, seg_cap);
    final_k<<<B, SORT_T, 0, stream>>>(neur, score, topkidx, tcount, out);
}

// Round 7
// 189.126 us; speedup vs baseline: 13.8941x; 1.0654x over previous
//
#include <hip/hip_runtime.h>
#include <math.h>

typedef unsigned int u32;
typedef unsigned long long u64;

#define B 8
#define H 1024
#define W 1536
#define NPIX (H * W)
#define NK 2048
#define BORDER 16
#define NSEG 64
#define TY 8
#define NTILE 6            // W / 256
#define GRIDY 31           // 992 rows / (TY * 4 waves)
#define HBINS 512
#define TOPK_CAP 4096
#define SORT_N 4096
#define SORT_T 512
#define SEG_CAP_MAX 4096
#define CTR_PAD 32
#define IDX_MASK 0x1FFFFFu

// workspace layout (bytes)
#define OFF_TCOUNT 128      // u32[B*CTR_PAD]                 -> [128, 1152)
#define OFF_HIST   4096     // u32[B*HBINS]                   -> [4096, 20480)
#define OFF_SEGCNT 20480    // u32[B*NSEG*CTR_PAD]            -> [20480, 86016)
#define OFF_KEYS   86016    // u64[B*TOPK_CAP]                -> [86016, 348160)
#define OFF_SORTED 348160   // u64[B*NK]                      -> [348160, 479232)
#define OFF_CAND   479232   // u32[B*NSEG*seg_cap]

__global__ __launch_bounds__(256) void cand_k(const float* __restrict__ neur,
                                              const float* __restrict__ score,
                                              u32* __restrict__ candp,
                                              u32* __restrict__ segcnt,
                                              u32* __restrict__ hist, int seg_cap) {
    __shared__ u32 lh[HBINS];
    int tile = blockIdx.x;
    int b = blockIdx.z;
    int wave = threadIdx.x >> 6;
    int lane = threadIdx.x & 63;
    for (int i = threadIdx.x; i < HBINS; i += 256) lh[i] = 0;
    __syncthreads();

    int strip = blockIdx.y * 4 + wave;
    int y0 = BORDER + strip * TY;
    int x0 = tile * 256 + lane * 4;
    const float* s = score + (size_t)b * NPIX;
    const float* nb = neur + (size_t)b * NPIX;
    bool haveL = (tile > 0) && (lane == 0);
    bool haveR = (tile < NTILE - 1) && (lane == 63);

    // preload all TY+2 rows (independent loads)
    float4 rv[TY + 2];
    float le[TY + 2], re[TY + 2];
    const float* base_row = s + (size_t)(y0 - 1) * W + x0;
    #pragma unroll
    for (int r = 0; r < TY + 2; ++r) rv[r] = *(const float4*)(base_row + (size_t)r * W);
    #pragma unroll
    for (int r = 0; r < TY + 2; ++r) {
        le[r] = haveL ? base_row[(size_t)r * W - 1] : 0.0f;
        re[r] = haveR ? base_row[(size_t)r * W + 4] : 0.0f;
    }

    bool xok[4];
    #pragma unroll
    for (int e = 0; e < 4; ++e) {
        int x = x0 + e;
        xok[e] = (x >= BORDER) && (x < W - BORDER);
    }

    // phase A: pure register compute of all ext bits
    u32 extbits = 0;
    {
        float4 hm, h0, hp;
        #pragma unroll
        for (int r = 0; r < 2; ++r) {
            float4 c = rv[r];
            float l = __shfl_up(c.w, 1); if (haveL) l = le[r];
            float rr = __shfl_down(c.x, 1); if (haveR) rr = re[r];
            float4 hh;
            hh.x = fmaxf(fmaxf(l, c.x), c.y);
            hh.y = fmaxf(fmaxf(c.x, c.y), c.z);
            hh.z = fmaxf(fmaxf(c.y, c.z), c.w);
            hh.w = fmaxf(fmaxf(c.z, c.w), rr);
            if (r == 0) hm = hh; else h0 = hh;
        }
        #pragma unroll
        for (int ys = 0; ys < TY; ++ys) {
            float4 c = rv[ys + 2];
            float l = __shfl_up(c.w, 1); if (haveL) l = le[ys + 2];
            float rr = __shfl_down(c.x, 1); if (haveR) rr = re[ys + 2];
            hp.x = fmaxf(fmaxf(l, c.x), c.y);
            hp.y = fmaxf(fmaxf(c.x, c.y), c.z);
            hp.z = fmaxf(fmaxf(c.y, c.z), c.w);
            hp.w = fmaxf(fmaxf(c.z, c.w), rr);
            float pv[4];
            pv[0] = fmaxf(fmaxf(hm.x, h0.x), hp.x);
            pv[1] = fmaxf(fmaxf(hm.y, h0.y), hp.y);
            pv[2] = fmaxf(fmaxf(hm.z, h0.z), hp.z);
            pv[3] = fmaxf(fmaxf(hm.w, h0.w), hp.w);
            float4 c0 = rv[ys + 1];
            float cv[4] = {c0.x, c0.y, c0.z, c0.w};
            #pragma unroll
            for (int e = 0; e < 4; ++e)
                if (xok[e] && cv[e] >= pv[e]) extbits |= (1u << (ys * 4 + e));
            hm = h0; h0 = hp;
        }
    }

    // phase B: one wave scan + one leader atomic, then independent gathers
    u32 c = (u32)__popc(extbits);
    u32 scan = c;
    #pragma unroll
    for (int off = 1; off < 64; off <<= 1) {
        u32 o = (u32)__shfl_up((int)scan, off, 64);
        if (lane >= off) scan += o;
    }
    u32 excl = scan - c;
    u32 tot = (u32)__shfl((int)scan, 63, 64);
    if (tot) {
        int seg = (strip * NTILE + tile) & (NSEG - 1);
        u32* ctr = &segcnt[(u32)(b * NSEG + seg) * CTR_PAD];
        u32 base = 0;
        if (lane == 63) base = atomicAdd(ctr, scan);
        base = (u32)__shfl((int)base, 63, 64);
        u32 pos0 = base + excl;
        u32 sbase = (u32)(b * NSEG + seg) * (u32)seg_cap;
        u32 idxbase = (u32)(y0 * W + x0);
        #pragma unroll
        for (int k = 0; k < 32; ++k) {
            if (extbits & (1u << k)) {
                u32 idx = idxbase + (u32)(k >> 2) * W + (u32)(k & 3);
                float nv = fmaxf(nb[idx], 0.0f);
                u32 fb = __float_as_uint(nv);
                u32 bin = fb >> 21; if (bin > HBINS - 1) bin = HBINS - 1;
                atomicAdd(&lh[bin], 1u);
                u32 p = pos0 + (u32)__popc(extbits & ((1u << k) - 1u));
                if ((int)p < seg_cap) candp[sbase + p] = (bin << 21) | idx;
            }
        }
    }
    __syncthreads();
    for (int i = threadIdx.x; i < HBINS; i += 256) {
        u32 v = lh[i];
        if (v) atomicAdd(&hist[(u32)b * HBINS + i], v);
    }
}

__global__ __launch_bounds__(256) void compact_k(const u32* __restrict__ candp,
                                                 const u32* __restrict__ segcnt,
                                                 const u32* __restrict__ hist,
                                                 const float* __restrict__ neur,
                                                 u64* __restrict__ keysout,
                                                 u32* tcount, int seg_cap) {
    __shared__ u32 piv_s;
    int seg = blockIdx.x;
    int b = blockIdx.y;
    int lane = threadIdx.x & 63;
    // wave 0: recompute pivot from hist (512 bins, 8/lane + shfl scan)
    if (threadIdx.x < 64) {
        if (threadIdx.x == 0) piv_s = 0xFFFFFFFFu;
        u32 v[8];
        u32 s8 = 0;
        #pragma unroll
        for (int e = 0; e < 8; ++e) {
            v[e] = hist[(u32)b * HBINS + (u32)threadIdx.x * 8u + e];
            s8 += v[e];
        }
        u32 incl = s8;
        #pragma unroll
        for (int off = 1; off < 64; off <<= 1) {
            u32 o = (u32)__shfl_up((int)incl, off, 64);
            if (lane >= off) incl += o;
        }
        u32 excl = incl - s8;
        if (excl < NK && incl >= NK) {
            u32 cum = excl;
            u32 T = 0;
            #pragma unroll
            for (int e = 0; e < 8; ++e) {
                cum += v[e];
                if (cum >= NK) { T = (u32)threadIdx.x * 8u + e; break; }
            }
            piv_s = (T + 2u) << 21;  // include bins <= T+1 entirely
        }
    }
    __syncthreads();
    u32 piv = piv_s;
    const float* nb = neur + (size_t)b * NPIX;

    u32 cnt = segcnt[(u32)(b * NSEG + seg) * CTR_PAD];
    if ((int)cnt > seg_cap) cnt = (u32)seg_cap;
    u32 base = (u32)(b * NSEG + seg) * (u32)seg_cap;
    u32 iters = (cnt + 255u) / 256u;
    for (u32 it = 0; it < iters; ++it) {
        u32 i = it * 256u + threadIdx.x;
        bool f = false;
        u32 idx = 0;
        if (i < cnt) {
            u32 p = candp[base + i];
            f = (p < piv);
            idx = p & IDX_MASK;
        }
        u64 m = __ballot((int)f);
        if (m) {
            int leader = __ffsll((long long)m) - 1;
            u32 wbase = 0;
            if (lane == leader) wbase = atomicAdd(&tcount[b * CTR_PAD], (u32)__popcll(m));
            wbase = (u32)__shfl((int)wbase, leader, 64);
            if (f) {
                u32 pos = wbase + (u32)__popcll(m & ((1ull << (u32)lane) - 1ull));
                if (pos < TOPK_CAP) {
                    float nv = fmaxf(nb[idx], 0.0f);
                    float ness = (float)exp(-(double)nv);  // correctly-rounded f32 exp
                    keysout[(u32)b * TOPK_CAP + pos] =
                        ((u64)__float_as_uint(ness) << 32) | (u32)(~idx);
                }
            }
        }
    }
}

// swizzled LDS slot: i + (i>>4) cuts u64 stride conflicts to ~2-4-way
__device__ __forceinline__ u32 sw(u32 i) { return i + (i >> 4); }

__device__ __forceinline__ void cex(u64& a, u64& b, bool desc) {
    bool swp = desc ? (a < b) : (a > b);
    if (swp) { u64 tmp = a; a = b; b = tmp; }
}

__global__ __launch_bounds__(SORT_T) void sort_k(const u64* __restrict__ keysin,
                                                 const u32* __restrict__ tcount,
                                                 u64* __restrict__ sorted) {
    __shared__ u64 keys[SORT_N + (SORT_N >> 4)];
    int b = blockIdx.x;
    u32 t = threadIdx.x;
    u32 cnt = tcount[b * CTR_PAD];
    if (cnt > TOPK_CAP) cnt = TOPK_CAP;
    for (u32 i = t; i < SORT_N; i += SORT_T)
        keys[sw(i)] = (i < cnt) ? keysin[(u32)b * TOPK_CAP + i] : 0ull;
    __syncthreads();

    // local phase: k=2,4,8 exact network on contiguous 8-blocks
    {
        u64 r[8];
        u32 base = t * 8u;
        #pragma unroll
        for (int e = 0; e < 8; ++e) r[e] = keys[sw(base + e)];
        cex(r[0], r[1], true);  cex(r[2], r[3], false);
        cex(r[4], r[5], true);  cex(r[6], r[7], false);
        cex(r[0], r[2], true);  cex(r[1], r[3], true);
        cex(r[4], r[6], false); cex(r[5], r[7], false);
        cex(r[0], r[1], true);  cex(r[2], r[3], true);
        cex(r[4], r[5], false); cex(r[6], r[7], false);
        bool d = ((base & 8u) == 0u);
        cex(r[0], r[4], d); cex(r[1], r[5], d); cex(r[2], r[6], d); cex(r[3], r[7], d);
        cex(r[0], r[2], d); cex(r[1], r[3], d); cex(r[4], r[6], d); cex(r[5], r[7], d);
        cex(r[0], r[1], d); cex(r[2], r[3], d); cex(r[4], r[5], d); cex(r[6], r[7], d);
        #pragma unroll
        for (int e = 0; e < 8; ++e) keys[sw(base + e)] = r[e];
    }
    __syncthreads();

    for (u32 k = 16; k <= SORT_N; k <<= 1) {
        u32 j = k >> 1;
        while (j >= 4) {
            u32 j0 = j >> 2;
            u32 base = ((t & ~(j0 - 1u)) << 3) | (t & (j0 - 1u));
            bool d = ((base & k) == 0u);
            u64 r[8];
            #pragma unroll
            for (int e = 0; e < 8; ++e) r[e] = keys[sw(base + (u32)e * j0)];
            cex(r[0], r[4], d); cex(r[1], r[5], d); cex(r[2], r[6], d); cex(r[3], r[7], d);
            cex(r[0], r[2], d); cex(r[1], r[3], d); cex(r[4], r[6], d); cex(r[5], r[7], d);
            cex(r[0], r[1], d); cex(r[2], r[3], d); cex(r[4], r[5], d); cex(r[6], r[7], d);
            #pragma unroll
            for (int e = 0; e < 8; ++e) keys[sw(base + (u32)e * j0)] = r[e];
            __syncthreads();
            j >>= 3;
        }
        if (j == 2) {
            #pragma unroll
            for (u32 m = 0; m < 2; ++m) {
                u32 vt = t + m * SORT_T;
                u32 base = vt << 2;
                bool d = ((base & k) == 0u);
                u64 r0 = keys[sw(base)], r1 = keys[sw(base + 1)];
                u64 r2 = keys[sw(base + 2)], r3 = keys[sw(base + 3)];
                cex(r0, r2, d); cex(r1, r3, d);
                cex(r0, r1, d); cex(r2, r3, d);
                keys[sw(base)] = r0; keys[sw(base + 1)] = r1;
                keys[sw(base + 2)] = r2; keys[sw(base + 3)] = r3;
            }
            __syncthreads();
        } else if (j == 1) {
            #pragma unroll
            for (u32 m = 0; m < 4; ++m) {
                u32 vt = t + m * SORT_T;
                u32 base = vt << 1;
                bool d = ((base & k) == 0u);
                u64 r0 = keys[sw(base)], r1 = keys[sw(base + 1)];
                cex(r0, r1, d);
                keys[sw(base)] = r0; keys[sw(base + 1)] = r1;
            }
            __syncthreads();
        }
    }

    for (u32 i = t; i < NK; i += SORT_T)
        sorted[(u32)b * NK + i] = keys[sw(i)];
}

__global__ __launch_bounds__(256) void refine_k(const float* __restrict__ neur,
                                                const float* __restrict__ score,
                                                const u64* __restrict__ sorted,
                                                float* __restrict__ out) {
    int b = blockIdx.y;
    u32 i = blockIdx.x * 256u + threadIdx.x;
    const float* s = score + (size_t)b * NPIX;
    const float* nb = neur + (size_t)b * NPIX;
    u64 key = sorted[(u32)b * NK + i];
    u32 idx = ~(u32)key;
    int y = (int)(idx / W), x = (int)(idx % W);
    int yc = min(max(y, 1), H - 2), xc = min(max(x, 1), W - 2);
    int p = yc * W + xc;
    float s00 = s[p], sp0 = s[p + W], sm0 = s[p - W], s0p = s[p + 1], s0m = s[p - 1];
    float spp = s[p + W + 1], spm = s[p + W - 1], smp = s[p - W + 1], smm = s[p - W - 1];
    float gy = 0.5f * (sp0 - sm0);
    float gx = 0.5f * (s0p - s0m);
    float hyy = sp0 - 2.0f * s00 + sm0;
    float hxx = s0p - 2.0f * s00 + s0m;
    float hxy = 0.25f * (spp - spm - smp + smm);
    float det = hyy * hxx - hxy * hxy;
    bool sing = fabsf(det) > 1e-12f;
    float sd = sing ? det : 1.0f;
    float iy = -(hxx * gy - hxy * gx) / sd;
    float ix = -(hyy * gx - hxy * gy) / sd;
    if (!sing) { iy = 0.0f; ix = 0.0f; }
    iy = fminf(fmaxf(iy, -0.5f), 0.5f);
    ix = fminf(fmaxf(ix, -0.5f), 0.5f);
    size_t o = ((size_t)b * NK + (size_t)i) * 3;
    out[o] = (float)y + 0.5f + iy;
    out[o + 1] = (float)x + 0.5f + ix;
    out[o + 2] = fmaxf(nb[idx], 0.0f);
}

extern "C" void kernel_launch(void* const* d_in, const int* in_sizes, int n_in,
                              void* d_out, int out_size, void* d_ws, size_t ws_size,
                              hipStream_t stream) {
    const float* neur = (const float*)d_in[0];
    const float* score = (const float*)d_in[1];
    float* out = (float*)d_out;
    char* ws = (char*)d_ws;
    u32* tcount = (u32*)(ws + OFF_TCOUNT);
    u32* hist = (u32*)(ws + OFF_HIST);
    u32* segcnt = (u32*)(ws + OFF_SEGCNT);
    u64* keysbuf = (u64*)(ws + OFF_KEYS);
    u64* sorted = (u64*)(ws + OFF_SORTED);
    u32* candp = (u32*)(ws + OFF_CAND);

    size_t avail = ws_size > OFF_CAND ? ws_size - OFF_CAND : 0;
    long long cap_ll = (long long)(avail / (4ull * B * NSEG));
    int seg_cap = cap_ll > SEG_CAP_MAX ? SEG_CAP_MAX : (int)cap_ll;

    // zero tcount/hist/segcnt in one memset node
    hipMemsetAsync(ws, 0, OFF_KEYS, stream);
    cand_k<<<dim3(NTILE, GRIDY, B), 256, 0, stream>>>(neur, score, candp, segcnt, hist, seg_cap);
    compact_k<<<dim3(NSEG, B), 256, 0, stream>>>(candp, segcnt, hist, neur, keysbuf, tcount, seg_cap);
    sort_k<<<B, SORT_T, 0, stream>>>(keysbuf, tcount, sorted);
    refine_k<<<dim3(NK / 256, B), 256, 0, stream>>>(neur, score, sorted, out);
}

// Round 9
// 178.124 us; speedup vs baseline: 14.7523x; 1.0618x over previous
//
#include <hip/hip_runtime.h>
#include <math.h>

typedef unsigned int u32;
typedef unsigned long long u64;

#define B 8
#define H 1024
#define W 1536
#define NPIX (H * W)
#define NK 2048
#define BORDER 16
#define NSEG 64
#define TY 8
#define NTILE 6            // W / 256
#define GRIDY 31           // 992 rows / (TY * 4 waves)
#define HBINS 512
#define TOPK_CAP 4096
#define SEG_CAP_MAX 4096
#define CTR_PAD 32
#define IDX_MASK 0x1FFFFFu

// workspace layout (bytes) — [0, OFF_CAND) is zeroed by one memset
#define OFF_TCOUNT 128      // u32[B*CTR_PAD]            ends 1152
#define OFF_HIST   4096     // u32[B*HBINS]              ends 20480
#define OFF_SEGCNT 20480    // u32[B*NSEG*CTR_PAD]       ends 86016
#define OFF_RANK   86016    // u32[B*TOPK_CAP]           ends 217088
#define OFF_KEYS   217088   // u64[B*TOPK_CAP]           ends 479232
#define OFF_CAND   479232   // u32[B*NSEG*seg_cap]  (disjoint from keys!)

__global__ __launch_bounds__(256) void cand_k(const float* __restrict__ neur,
                                              const float* __restrict__ score,
                                              u32* __restrict__ candp,
                                              u32* __restrict__ segcnt,
                                              u32* __restrict__ hist, int seg_cap) {
    __shared__ u32 lh[HBINS];
    int tile = blockIdx.x;
    int b = blockIdx.z;
    int wave = threadIdx.x >> 6;
    int lane = threadIdx.x & 63;
    for (int i = threadIdx.x; i < HBINS; i += 256) lh[i] = 0;
    __syncthreads();

    int strip = blockIdx.y * 4 + wave;
    int y0 = BORDER + strip * TY;
    int x0 = tile * 256 + lane * 4;
    const float* s = score + (size_t)b * NPIX;
    const float* nb = neur + (size_t)b * NPIX;
    bool haveL = (tile > 0) && (lane == 0);
    bool haveR = (tile < NTILE - 1) && (lane == 63);

    // preload: 10 score rows + 8 neur rows, all independent (one vmcnt burst)
    float4 rv[TY + 2];
    float4 nvv[TY];
    float le[TY + 2], re[TY + 2];
    const float* base_row = s + (size_t)(y0 - 1) * W + x0;
    const float* nrow = nb + (size_t)y0 * W + x0;
    #pragma unroll
    for (int r = 0; r < TY + 2; ++r) rv[r] = *(const float4*)(base_row + (size_t)r * W);
    #pragma unroll
    for (int r = 0; r < TY; ++r) nvv[r] = *(const float4*)(nrow + (size_t)r * W);
    #pragma unroll
    for (int r = 0; r < TY + 2; ++r) {
        le[r] = haveL ? base_row[(size_t)r * W - 1] : 0.0f;
        re[r] = haveR ? base_row[(size_t)r * W + 4] : 0.0f;
    }

    bool xok[4];
    #pragma unroll
    for (int e = 0; e < 4; ++e) {
        int x = x0 + e;
        xok[e] = (x >= BORDER) && (x < W - BORDER);
    }

    // phase A: pure register compute of all ext bits
    u32 extbits = 0;
    {
        float4 hm, h0, hp;
        #pragma unroll
        for (int r = 0; r < 2; ++r) {
            float4 c = rv[r];
            float l = __shfl_up(c.w, 1); if (haveL) l = le[r];
            float rr = __shfl_down(c.x, 1); if (haveR) rr = re[r];
            float4 hh;
            hh.x = fmaxf(fmaxf(l, c.x), c.y);
            hh.y = fmaxf(fmaxf(c.x, c.y), c.z);
            hh.z = fmaxf(fmaxf(c.y, c.z), c.w);
            hh.w = fmaxf(fmaxf(c.z, c.w), rr);
            if (r == 0) hm = hh; else h0 = hh;
        }
        #pragma unroll
        for (int ys = 0; ys < TY; ++ys) {
            float4 c = rv[ys + 2];
            float l = __shfl_up(c.w, 1); if (haveL) l = le[ys + 2];
            float rr = __shfl_down(c.x, 1); if (haveR) rr = re[ys + 2];
            hp.x = fmaxf(fmaxf(l, c.x), c.y);
            hp.y = fmaxf(fmaxf(c.x, c.y), c.z);
            hp.z = fmaxf(fmaxf(c.y, c.z), c.w);
            hp.w = fmaxf(fmaxf(c.z, c.w), rr);
            float pv[4];
            pv[0] = fmaxf(fmaxf(hm.x, h0.x), hp.x);
            pv[1] = fmaxf(fmaxf(hm.y, h0.y), hp.y);
            pv[2] = fmaxf(fmaxf(hm.z, h0.z), hp.z);
            pv[3] = fmaxf(fmaxf(hm.w, h0.w), hp.w);
            float4 c0 = rv[ys + 1];
            float cv[4] = {c0.x, c0.y, c0.z, c0.w};
            #pragma unroll
            for (int e = 0; e < 4; ++e)
                if (xok[e] && cv[e] >= pv[e]) extbits |= (1u << (ys * 4 + e));
            hm = h0; h0 = hp;
        }
    }

    // phase B: one wave scan + one leader atomic; nv already in registers
    u32 c = (u32)__popc(extbits);
    u32 scan = c;
    #pragma unroll
    for (int off = 1; off < 64; off <<= 1) {
        u32 o = (u32)__shfl_up((int)scan, off, 64);
        if (lane >= off) scan += o;
    }
    u32 excl = scan - c;
    u32 tot = (u32)__shfl((int)scan, 63, 64);
    if (tot) {
        int seg = (strip * NTILE + tile) & (NSEG - 1);
        u32* ctr = &segcnt[(u32)(b * NSEG + seg) * CTR_PAD];
        u32 base = 0;
        if (lane == 63) base = atomicAdd(ctr, scan);
        base = (u32)__shfl((int)base, 63, 64);
        u32 pos0 = base + excl;
        u32 sbase = (u32)(b * NSEG + seg) * (u32)seg_cap;
        u32 idxbase = (u32)(y0 * W + x0);
        #pragma unroll
        for (int k = 0; k < 32; ++k) {
            if (extbits & (1u << k)) {
                const int ro = k >> 2, e = k & 3;
                float4 nq = nvv[ro];
                float raw = (e == 0) ? nq.x : (e == 1) ? nq.y : (e == 2) ? nq.z : nq.w;
                float nv = fmaxf(raw, 0.0f);
                u32 fb = __float_as_uint(nv);
                u32 bin = fb >> 21; if (bin > HBINS - 1) bin = HBINS - 1;
                atomicAdd(&lh[bin], 1u);
                u32 idx = idxbase + (u32)ro * W + (u32)e;
                u32 p = pos0 + (u32)__popc(extbits & ((1u << k) - 1u));
                if ((int)p < seg_cap) candp[sbase + p] = (bin << 21) | idx;
            }
        }
    }
    __syncthreads();
    for (int i = threadIdx.x; i < HBINS; i += 256) {
        u32 v = lh[i];
        if (v) atomicAdd(&hist[(u32)b * HBINS + i], v);
    }
}

__global__ __launch_bounds__(256) void compact_k(const u32* __restrict__ candp,
                                                 const u32* __restrict__ segcnt,
                                                 const u32* __restrict__ hist,
                                                 const float* __restrict__ neur,
                                                 u64* __restrict__ keysout,
                                                 u32* tcount, int seg_cap) {
    __shared__ u32 piv_s;
    int seg = blockIdx.x;
    int b = blockIdx.y;
    int lane = threadIdx.x & 63;
    // wave 0: recompute pivot from hist (512 bins, 8/lane + shfl scan)
    if (threadIdx.x < 64) {
        if (threadIdx.x == 0) piv_s = 0xFFFFFFFFu;
        u32 v[8];
        u32 s8 = 0;
        #pragma unroll
        for (int e = 0; e < 8; ++e) {
            v[e] = hist[(u32)b * HBINS + (u32)threadIdx.x * 8u + e];
            s8 += v[e];
        }
        u32 incl = s8;
        #pragma unroll
        for (int off = 1; off < 64; off <<= 1) {
            u32 o = (u32)__shfl_up((int)incl, off, 64);
            if (lane >= off) incl += o;
        }
        u32 excl = incl - s8;
        if (excl < NK && incl >= NK) {
            u32 cum = excl;
            u32 T = 0;
            #pragma unroll
            for (int e = 0; e < 8; ++e) {
                cum += v[e];
                if (cum >= NK) { T = (u32)threadIdx.x * 8u + e; break; }
            }
            piv_s = (T + 2u) << 21;  // include bins <= T+1 entirely
        }
    }
    __syncthreads();
    u32 piv = piv_s;
    const float* nb = neur + (size_t)b * NPIX;

    u32 cnt = segcnt[(u32)(b * NSEG + seg) * CTR_PAD];
    if ((int)cnt > seg_cap) cnt = (u32)seg_cap;
    u32 base = (u32)(b * NSEG + seg) * (u32)seg_cap;
    u32 iters = (cnt + 255u) / 256u;
    for (u32 it = 0; it < iters; ++it) {
        u32 i = it * 256u + threadIdx.x;
        bool f = false;
        u32 idx = 0;
        if (i < cnt) {
            u32 p = candp[base + i];
            f = (p < piv);
            idx = p & IDX_MASK;
        }
        u64 m = __ballot((int)f);
        if (m) {
            int leader = __ffsll((long long)m) - 1;
            u32 wbase = 0;
            if (lane == leader) wbase = atomicAdd(&tcount[b * CTR_PAD], (u32)__popcll(m));
            wbase = (u32)__shfl((int)wbase, leader, 64);
            if (f) {
                u32 pos = wbase + (u32)__popcll(m & ((1ull << (u32)lane) - 1ull));
                if (pos < TOPK_CAP) {
                    float nv = fmaxf(nb[idx], 0.0f);
                    float ness = (float)exp(-(double)nv);  // correctly-rounded f32 exp
                    keysout[(u32)b * TOPK_CAP + pos] =
                        ((u64)__float_as_uint(ness) << 32) | (u32)(~idx);
                }
            }
        }
    }
}

// exact descending rank: rank[i] = #{j : key_j > key_i}; keys distinct,
// zero-padded tail ranks >= cnt >= NK so never selected.
__global__ __launch_bounds__(1024) void rank_k(const u64* __restrict__ keys,
                                               u32* __restrict__ rank) {
    __shared__ u64 jk[1024];
    int b = blockIdx.z;
    u32 i = blockIdx.x * 1024u + threadIdx.x;
    u64 ki = keys[(u32)b * TOPK_CAP + i];
    jk[threadIdx.x] = keys[(u32)b * TOPK_CAP + blockIdx.y * 1024u + threadIdx.x];
    __syncthreads();
    u32 r = 0;
    #pragma unroll 8
    for (int j = 0; j < 1024; ++j) r += (jk[j] > ki) ? 1u : 0u;
    if (r) atomicAdd(&rank[(u32)b * TOPK_CAP + i], r);
}

__global__ __launch_bounds__(256) void refine_k(const float* __restrict__ neur,
                                                const float* __restrict__ score,
                                                const u64* __restrict__ keys,
                                                const u32* __restrict__ rank,
                                                float* __restrict__ out) {
    int b = blockIdx.y;
    u32 i = blockIdx.x * 256u + threadIdx.x;
    u32 r = rank[(u32)b * TOPK_CAP + i];
    if (r >= NK) return;
    const float* s = score + (size_t)b * NPIX;
    const float* nb = neur + (size_t)b * NPIX;
    u64 key = keys[(u32)b * TOPK_CAP + i];
    u32 idx = ~(u32)key;
    if (idx >= (u32)NPIX) return;  // defensive: never true for legitimate keys
    int y = (int)(idx / W), x = (int)(idx % W);
    int yc = min(max(y, 1), H - 2), xc = min(max(x, 1), W - 2);
    int p = yc * W + xc;
    float s00 = s[p], sp0 = s[p + W], sm0 = s[p - W], s0p = s[p + 1], s0m = s[p - 1];
    float spp = s[p + W + 1], spm = s[p + W - 1], smp = s[p - W + 1], smm = s[p - W - 1];
    float gy = 0.5f * (sp0 - sm0);
    float gx = 0.5f * (s0p - s0m);
    float hyy = sp0 - 2.0f * s00 + sm0;
    float hxx = s0p - 2.0f * s00 + s0m;
    float hxy = 0.25f * (spp - spm - smp + smm);
    float det = hyy * hxx - hxy * hxy;
    bool sing = fabsf(det) > 1e-12f;
    float sd = sing ? det : 1.0f;
    float iy = -(hxx * gy - hxy * gx) / sd;
    float ix = -(hyy * gx - hxy * gy) / sd;
    if (!sing) { iy = 0.0f; ix = 0.0f; }
    iy = fminf(fmaxf(iy, -0.5f), 0.5f);
    ix = fminf(fmaxf(ix, -0.5f), 0.5f);
    size_t o = ((size_t)b * NK + (size_t)r) * 3;
    out[o] = (float)y + 0.5f + iy;
    out[o + 1] = (float)x + 0.5f + ix;
    out[o + 2] = fmaxf(nb[idx], 0.0f);
}

extern "C" void kernel_launch(void* const* d_in, const int* in_sizes, int n_in,
                              void* d_out, int out_size, void* d_ws, size_t ws_size,
                              hipStream_t stream) {
    const float* neur = (const float*)d_in[0];
    const float* score = (const float*)d_in[1];
    float* out = (float*)d_out;
    char* ws = (char*)d_ws;
    u32* tcount = (u32*)(ws + OFF_TCOUNT);
    u32* hist = (u32*)(ws + OFF_HIST);
    u32* segcnt = (u32*)(ws + OFF_SEGCNT);
    u32* rank = (u32*)(ws + OFF_RANK);
    u64* keysbuf = (u64*)(ws + OFF_KEYS);
    u32* candp = (u32*)(ws + OFF_CAND);

    size_t avail = ws_size > OFF_CAND ? ws_size - OFF_CAND : 0;
    long long cap_ll = (long long)(avail / (4ull * B * NSEG));
    int seg_cap = cap_ll > SEG_CAP_MAX ? SEG_CAP_MAX : (int)cap_ll;

    // zero tcount/hist/segcnt/rank/keys in one memset node
    hipMemsetAsync(ws, 0, OFF_CAND, stream);
    cand_k<<<dim3(NTILE, GRIDY, B), 256, 0, stream>>>(neur, score, candp, segcnt, hist, seg_cap);
    compact_k<<<dim3(NSEG, B), 256, 0, stream>>>(candp, segcnt, hist, neur, keysbuf, tcount, seg_cap);
    rank_k<<<dim3(TOPK_CAP / 1024, TOPK_CAP / 1024, B), 1024, 0, stream>>>(keysbuf, rank);
    refine_k<<<dim3(TOPK_CAP / 256, B), 256, 0, stream>>>(neur, score, keysbuf, rank, out);
}